// Round 17
// baseline (274.768 us; speedup 1.0000x reference)
//
#include <hip/hip_runtime.h>
#include <hip/hip_bf16.h>

typedef unsigned short u16;
typedef __attribute__((ext_vector_type(8))) short s16x8;
typedef __attribute__((ext_vector_type(8))) unsigned short u16x8;
typedef __attribute__((ext_vector_type(4))) float f32x4;

#define SEQ 2048
#define KEXP 0.18033688011112042f  /* 0.125 * log2(e) */

__device__ __forceinline__ float bf2f(u16 x) {
  union { unsigned u; float f; } c; c.u = ((unsigned)x) << 16; return c.f;
}
// hardware bf16 convert (v_cvt_pk_bf16_f32 on gfx950)
__device__ __forceinline__ u16 f2bf(float f) {
  __hip_bfloat16 h = __float2bfloat16(f);
  return __builtin_bit_cast(u16, h);
}
__device__ __forceinline__ unsigned pack2(float a, float b) {
  return (unsigned)f2bf(a) | ((unsigned)f2bf(b) << 16);
}
// async global->LDS, 16B per lane; LDS dest = wave-uniform base + lane*16
__device__ __forceinline__ void gload_lds16(const u16* g, u16* l) {
  __builtin_amdgcn_global_load_lds(
      (const __attribute__((address_space(1))) void*)g,
      (__attribute__((address_space(3))) void*)l, 16, 0, 0);
}

// ---------------- fp32 -> bf16 flat convert ----------------
__global__ __launch_bounds__(256) void k_cvt(const float* __restrict__ src,
                                             u16* __restrict__ dst, int n4) {
  int i = blockIdx.x * 256 + threadIdx.x;
  if (i >= n4) return;
  float4 v = ((const float4*)src)[i];
  ((ushort4*)dst)[i] = make_ushort4(f2bf(v.x), f2bf(v.y), f2bf(v.z), f2bf(v.w));
}

// ---------------- fp32 [R][C] -> bf16 [C][R] transpose-convert ----------------
__global__ __launch_bounds__(256) void k_tcvt(const float* __restrict__ src,
                                              u16* __restrict__ dst, int R, int C) {
  __shared__ u16 T[64][72];
  int r0 = blockIdx.y * 64, c0 = blockIdx.x * 64;
  int tid = threadIdx.x;
#pragma unroll
  for (int p = 0; p < 4; ++p) {
    int f = p * 256 + tid;            // float4 id within 64x64 tile
    int r = f >> 4, cc = (f & 15) * 4;
    float4 v = *(const float4*)(src + (size_t)(r0 + r) * C + c0 + cc);
    T[r][cc + 0] = f2bf(v.x); T[r][cc + 1] = f2bf(v.y);
    T[r][cc + 2] = f2bf(v.z); T[r][cc + 3] = f2bf(v.w);
  }
  __syncthreads();
#pragma unroll
  for (int p = 0; p < 2; ++p) {
    int f = p * 256 + tid;            // u16x8 chunk id
    int c = f >> 3, rr = (f & 7) * 8;
    u16x8 v;
#pragma unroll
    for (int e = 0; e < 8; ++e) v[e] = T[rr + e][c];
    *(u16x8*)(dst + (size_t)(c0 + c) * R + r0 + rr) = v;
  }
}

// ---------------- C[M,N] = A[M,K] @ Bt[N,K]^T  (bf16 in, bf16 or f32+res out) ----
// global_load_lds width=16 staging with BOTH-SIDES XOR swizzle (R16, proven).
template <int RES>
__global__ __launch_bounds__(256) void k_gemm_bt(const u16* __restrict__ A,
                                                 const u16* __restrict__ Bt,
                                                 u16* __restrict__ Cb,
                                                 float* __restrict__ Cf,
                                                 const float* __restrict__ res,
                                                 int M, int N, int K) {
  __shared__ u16 As[128 * 64];
  __shared__ u16 Bs[128 * 64];
  const int tid = threadIdx.x;
  const int l = tid & 63, wv = tid >> 6;
  const int g = l >> 4, c16 = l & 15;
  const int m0 = blockIdx.x * 128, n0 = blockIdx.y * 128;
  const int wr = (wv >> 1) * 64, wc = (wv & 1) * 64;
  const int lrow = l >> 3;                 // 0..7 within 8-row slot
  const int lchunk = (l & 7) ^ lrow;       // pre-swizzled source chunk
  f32x4 acc[4][4] = {};
  for (int k0 = 0; k0 < K; k0 += 64) {
    __syncthreads();
#pragma unroll
    for (int p = 0; p < 4; ++p) {
      int slot = wv * 4 + p;
      int row = slot * 8 + lrow;
      gload_lds16(A + (size_t)(m0 + row) * K + k0 + lchunk * 8, &As[slot * 512]);
      gload_lds16(Bt + (size_t)(n0 + row) * K + k0 + lchunk * 8, &Bs[slot * 512]);
    }
    __syncthreads();
#pragma unroll
    for (int ks = 0; ks < 2; ++ks) {
      s16x8 af[4], bf[4];
      const int rc = c16 & 7;
#pragma unroll
      for (int fr = 0; fr < 4; ++fr)
        af[fr] = *(const s16x8*)&As[(wr + fr * 16 + c16) * 64 +
                                    (((ks * 4 + g) ^ rc) * 8)];
#pragma unroll
      for (int fc = 0; fc < 4; ++fc)
        bf[fc] = *(const s16x8*)&Bs[(wc + fc * 16 + c16) * 64 +
                                    (((ks * 4 + g) ^ rc) * 8)];
#pragma unroll
      for (int fr = 0; fr < 4; ++fr)
#pragma unroll
        for (int fc = 0; fc < 4; ++fc)
          acc[fr][fc] = __builtin_amdgcn_mfma_f32_16x16x32_bf16(af[fr], bf[fc],
                                                                acc[fr][fc], 0, 0, 0);
    }
  }
#pragma unroll
  for (int fr = 0; fr < 4; ++fr)
#pragma unroll
    for (int fc = 0; fc < 4; ++fc)
#pragma unroll
      for (int reg = 0; reg < 4; ++reg) {
        int row = m0 + wr + fr * 16 + g * 4 + reg;
        int col = n0 + wc + fc * 16 + c16;
        float v = acc[fr][fc][reg];
        if (RES) Cf[(size_t)row * N + col] = v + res[(size_t)row * N + col];
        else     Cb[(size_t)row * N + col] = f2bf(v);
      }
}

// ---------------- build V^T [b][n][d][j] from qkv ----------------
__global__ __launch_bounds__(256) void k_vt(const u16* __restrict__ qkv,
                                            u16* __restrict__ vT) {
  __shared__ u16 T[64][72];
  const int tid = threadIdx.x;
  const int j0 = blockIdx.x * 64;
  const int n = blockIdx.y & 15, b = blockIdx.y >> 4;
#pragma unroll
  for (int p = 0; p < 2; ++p) {
    int f = p * 256 + tid;
    int r = f >> 3, cc = (f & 7) * 8;
    *(u16x8*)&T[r][cc] =
        *(const u16x8*)(qkv + ((size_t)((j0 + r) * 2 + b)) * 3072 + 2048 + n * 64 + cc);
  }
  __syncthreads();
#pragma unroll
  for (int p = 0; p < 2; ++p) {
    int f = p * 256 + tid;
    int d = f >> 3, jc = (f & 7) * 8;
    u16x8 v;
#pragma unroll
    for (int e = 0; e < 8; ++e) v[e] = T[jc + e][d];
    *(u16x8*)(vT + ((size_t)((b * 16 + n) * 64 + d)) * 2048 + j0 + jc) = v;
  }
}

// ---------------- fused rel-attention (KVBLK=64, swapped MFMA, 3 blocks/CU) ---
// vs R15: KVBLK 128 -> 64. LDS 79.4 -> 45.3KB (Kt[64][72]+Vt[64][72]+
// St2[65][136]+Pt[4][16][72]) => 3 blocks/CU; registers shrink (kpre/vpre/rpre
// halve, sc[8]->sc[4], ~-40 arch => ~3 waves/SIMD) => occupancy ~37% vs 21%.
// Cost: 32 iters (2x barriers, +16% MFMA from band overlap). Structure,
// rel-shift write-bake, static-shift softmax all R15-identical.
__global__ __launch_bounds__(256) void k_attn(const u16* __restrict__ qkv,
                                              const u16* __restrict__ rk,
                                              const u16* __restrict__ vT,
                                              const float* __restrict__ rwb,
                                              const float* __restrict__ rrb,
                                              u16* __restrict__ av) {
  __shared__ u16 Kt[64][72];    // K tile [j][d]
  __shared__ u16 Vt[64][72];    // V^T tile [d][j]
  __shared__ u16 St2[65 * 136]; // shifted band, physical row p = QR[p-1+delta]
  __shared__ u16 Pt[4][16][72]; // P strips, per wave [row=c16][jj]

  const int tid = threadIdx.x;
  const int l = tid & 63, wv = tid >> 6;
  const int g = l >> 4, c16 = l & 15;
  // XCD-aware swizzle: 4 consecutive bn per XCD -> K/V/rk L2-resident
  const int s = blockIdx.x;
  const int y = (s & 7) + 8 * (s >> 8);  // bn
  const int x = (s >> 3) & 31;           // i-tile
  const int i0 = x * 64;
  const int n = y & 15, b = y >> 4;
  const int ii = wv * 16 + c16;          // this lane's q-row (softmax domain)
  const f32x4 zero4 = {0.f, 0.f, 0.f, 0.f};
  const s16x8 zero8 = {0, 0, 0, 0, 0, 0, 0, 0};

  // ---- loop-invariant register fragments ----
  s16x8 qw[2];
  {
    int i = i0 + wv * 16 + c16;
    const u16* src = qkv + ((size_t)(i * 2 + b)) * 3072 + n * 64;
#pragma unroll
    for (int ks = 0; ks < 2; ++ks) {
      int d0 = ks * 32 + g * 8;
      u16x8 raw = *(const u16x8*)(src + d0);
      u16x8 wq;
#pragma unroll
      for (int e = 0; e < 8; ++e)
        wq[e] = f2bf(bf2f(raw[e]) + rwb[n * 64 + d0 + e]);
      qw[ks] = __builtin_bit_cast(s16x8, wq);
    }
  }
  s16x8 qr_b[4][2];
#pragma unroll
  for (int rb = 0; rb < 4; ++rb) {
    int i = i0 + rb * 16 + c16;
    const u16* src = qkv + ((size_t)(i * 2 + b)) * 3072 + n * 64;
#pragma unroll
    for (int ks = 0; ks < 2; ++ks) {
      int d0 = ks * 32 + g * 8;
      u16x8 raw = *(const u16x8*)(src + d0);
      u16x8 wq;
#pragma unroll
      for (int e = 0; e < 8; ++e)
        wq[e] = f2bf(bf2f(raw[e]) + rrb[n * 64 + d0 + e]);
      qr_b[rb][ks] = __builtin_bit_cast(s16x8, wq);
    }
  }
  s16x8 q64[2];
  {
    int i = i0 + 64; if (i > SEQ - 1) i = SEQ - 1;
    const u16* src = qkv + ((size_t)(i * 2 + b)) * 3072 + n * 64;
#pragma unroll
    for (int ks = 0; ks < 2; ++ks) {
      int d0 = ks * 32 + g * 8;
      u16x8 raw = *(const u16x8*)(src + d0);
      u16x8 wq;
#pragma unroll
      for (int e = 0; e < 8; ++e)
        wq[e] = f2bf(bf2f(raw[e]) + rrb[n * 64 + d0 + e]);
      q64[ks] = __builtin_bit_cast(s16x8, wq);
    }
  }

  // prefetch registers (issued during previous iteration's PV)
  u16x8 kpre[2], vpre[2];
  s16x8 rpre[2][2];
  auto issue_loads = [&](int j0n) {
#pragma unroll
    for (int p = 0; p < 2; ++p) {
      int f = p * 256 + tid;
      kpre[p] = *(const u16x8*)(qkv + ((size_t)((j0n + (f >> 3)) * 2 + b)) * 3072 +
                                1024 + n * 64 + (f & 7) * 8);
    }
#pragma unroll
    for (int p = 0; p < 2; ++p) {
      int f = p * 256 + tid;
      vpre[p] = *(const u16x8*)(vT + ((size_t)((b * 16 + n) * 64 + (f >> 3))) * 2048 +
                                j0n + (f & 7) * 8);
    }
#pragma unroll
    for (int c3 = 0; c3 < 2; ++c3) {
      int w = (wv * 2 + c3) * 16 + c16;
      int u = j0n - i0 - 63 + w;
      int c = (u <= 0) ? (u + (SEQ - 1)) : (u - 2);
      const u16* p = rk + (size_t)(c < 0 ? 0 : c) * 1024 + n * 64;
      rpre[c3][0] = *(const s16x8*)(p + g * 8);
      rpre[c3][1] = *(const s16x8*)(p + 32 + g * 8);
      if (c < 0) { rpre[c3][0] = zero8; rpre[c3][1] = zero8; }
    }
  };

  float l_sum = 0.f;
  f32x4 o_acc[4];
#pragma unroll
  for (int r = 0; r < 4; ++r) o_acc[r] = zero4;

  issue_loads(0);

  for (int it = 0; it < 32; ++it) {
    const int j0 = it * 64;
    const int wbthr = (64 + i0 - j0) >> 4;  // delta(wb) = (wb >= wbthr)
    __syncthreads();  // prev-iter St2/Kt/Vt reads complete

    // ds-write staged K/V (vmcnt hidden under previous PV)
#pragma unroll
    for (int p = 0; p < 2; ++p) {
      int f = p * 256 + tid;
      *(u16x8*)&Kt[f >> 3][(f & 7) * 8] = kpre[p];
    }
#pragma unroll
    for (int p = 0; p < 2; ++p) {
      int f = p * 256 + tid;
      *(u16x8*)&Vt[f >> 3][(f & 7) * 8] = vpre[p];
    }

    // QR_sw: D[w in regs][r in lanes]; rel-shift baked into WRITE ADDRESS:
    // physical row = r + 1 - delta(wb)  (wave-uniform offset)
#pragma unroll
    for (int c3 = 0; c3 < 2; ++c3) {
      const int wb = wv * 2 + c3;
      const int du = (wb >= wbthr) ? 1 : 0;  // wave-uniform
#pragma unroll
      for (int rb = 0; rb < 4; ++rb) {
        f32x4 q = zero4;
        q = __builtin_amdgcn_mfma_f32_16x16x32_bf16(rpre[c3][0], qr_b[rb][0], q, 0, 0, 0);
        q = __builtin_amdgcn_mfma_f32_16x16x32_bf16(rpre[c3][1], qr_b[rb][1], q, 0, 0, 0);
        uint2 pk;
        pk.x = pack2(q[0], q[1]);
        pk.y = pack2(q[2], q[3]);
        // row 0 (rb=0,c16=0,du=1) is the discard slot; rows 1..64 are live
        *(uint2*)&St2[(rb * 16 + c16 + 1 - du) * 136 + wb * 16 + g * 4] = pk;
      }
      // q64 extra row (QR[64][w]) -> physical row 64, only used where delta=1
      {
        f32x4 q = zero4;
        q = __builtin_amdgcn_mfma_f32_16x16x32_bf16(rpre[c3][0], q64[0], q, 0, 0, 0);
        q = __builtin_amdgcn_mfma_f32_16x16x32_bf16(rpre[c3][1], q64[1], q, 0, 0, 0);
        if (du && c16 == 0) {
          uint2 pk;
          pk.x = pack2(q[0], q[1]);
          pk.y = pack2(q[2], q[3]);
          *(uint2*)&St2[64 * 136 + wb * 16 + g * 4] = pk;
        }
      }
    }
    __syncthreads();  // Kt, Vt, St2 visible

    // AC_sw = mfma(K, Q): lane c16 = ii, regs = jj = fj*16 + g*4 + reg
    f32x4 sc[4];
#pragma unroll
    for (int fj = 0; fj < 4; ++fj) sc[fj] = zero4;
    __builtin_amdgcn_s_setprio(1);
#pragma unroll
    for (int ks = 0; ks < 2; ++ks)
#pragma unroll
      for (int fj = 0; fj < 4; ++fj) {
        s16x8 kf = *(const s16x8*)&Kt[fj * 16 + c16][ks * 32 + g * 8];
        sc[fj] = __builtin_amdgcn_mfma_f32_16x16x32_bf16(kf, qw[ks], sc[fj], 0, 0, 0);
      }
    __builtin_amdgcn_s_setprio(0);

    // gather BD: physical row ii+1, col w = jj-ii+63
    // offset = (ii+1)*136 + jj - ii + 63 = ii*135 + 199 + fj*16 + g*4 + reg
    {
      const u16* Sb = &St2[ii * 135 + 199 + g * 4];
#pragma unroll
      for (int fj = 0; fj < 4; ++fj)
#pragma unroll
        for (int reg = 0; reg < 4; ++reg)
          sc[fj][reg] += bf2f(Sb[fj * 16 + reg]);
    }

    // static-shift softmax: p = exp2(s * KEXP) directly (bounded scores)
    float rs = 0.f;
#pragma unroll
    for (int fj = 0; fj < 4; ++fj)
#pragma unroll
      for (int reg = 0; reg < 4; ++reg) {
        float p = __builtin_amdgcn_exp2f(sc[fj][reg] * KEXP);
        rs += p;
        sc[fj][reg] = p;  // reuse sc as P
      }
    rs += __shfl_xor(rs, 16);
    rs += __shfl_xor(rs, 32);
    l_sum += rs;

    // P -> own strip (aligned b64), then read back as A-frags (same wave)
#pragma unroll
    for (int fj = 0; fj < 4; ++fj) {
      uint2 pk;
      pk.x = pack2(sc[fj][0], sc[fj][1]);
      pk.y = pack2(sc[fj][2], sc[fj][3]);
      *(uint2*)&Pt[wv][c16][fj * 16 + g * 4] = pk;
    }

    // prefetch next tile's K/V/rk while PV runs
    if (it < 31) issue_loads(j0 + 64);

    // PV: O += P @ V (A = P strip, row = c16 = ii)
    __builtin_amdgcn_s_setprio(1);
#pragma unroll
    for (int ks = 0; ks < 2; ++ks) {
      s16x8 pa = *(const s16x8*)&Pt[wv][c16][ks * 32 + g * 8];
#pragma unroll
      for (int fd = 0; fd < 4; ++fd) {
        s16x8 vb = *(const s16x8*)&Vt[fd * 16 + c16][ks * 32 + g * 8];
        o_acc[fd] = __builtin_amdgcn_mfma_f32_16x16x32_bf16(pa, vb, o_acc[fd], 0, 0, 0);
      }
    }
    __builtin_amdgcn_s_setprio(0);
  }

  // epilogue: transpose 1/l across lanes (rows in reg-dim)
  float linv = 1.0f / l_sum;
  float linv_t[4];
#pragma unroll
  for (int reg = 0; reg < 4; ++reg)
    linv_t[reg] = __shfl(linv, g * 4 + reg, 64);
#pragma unroll
  for (int reg = 0; reg < 4; ++reg) {
    int i = i0 + wv * 16 + g * 4 + reg;
    u16* dst = av + ((size_t)(i * 2 + b)) * 1024 + n * 64;
#pragma unroll
    for (int fd = 0; fd < 4; ++fd)
      dst[fd * 16 + c16] = f2bf(o_acc[fd][reg] * linv_t[reg]);
  }
}

// ---------------- LayerNorm over rows of tmp (= attn_out + h) ----------------
__global__ __launch_bounds__(256) void k_ln(const float* __restrict__ tmp,
                                            const float* __restrict__ gamma,
                                            const float* __restrict__ beta,
                                            float* __restrict__ out) {
  __shared__ float r1[4], r2[4];
  const int row = blockIdx.x, tid = threadIdx.x;
  const float* x = tmp + (size_t)row * 1024;
  float4 v = *(const float4*)(x + tid * 4);
  float s1 = v.x + v.y + v.z + v.w;
  float s2 = v.x * v.x + v.y * v.y + v.z * v.z + v.w * v.w;
#pragma unroll
  for (int off = 1; off < 64; off <<= 1) {
    s1 += __shfl_xor(s1, off, 64);
    s2 += __shfl_xor(s2, off, 64);
  }
  if ((tid & 63) == 0) { r1[tid >> 6] = s1; r2[tid >> 6] = s2; }
  __syncthreads();
  s1 = r1[0] + r1[1] + r1[2] + r1[3];
  s2 = r2[0] + r2[1] + r2[2] + r2[3];
  float mu = s1 * (1.f / 1024.f);
  float var = s2 * (1.f / 1024.f) - mu * mu;
  float rstd = rsqrtf(var + 1e-6f);
  float4 gm = *(const float4*)(gamma + tid * 4);
  float4 bt = *(const float4*)(beta + tid * 4);
  float4 o;
  o.x = (v.x - mu) * rstd * gm.x + bt.x;
  o.y = (v.y - mu) * rstd * gm.y + bt.y;
  o.z = (v.z - mu) * rstd * gm.z + bt.z;
  o.w = (v.w - mu) * rstd * gm.w + bt.w;
  *(float4*)(out + (size_t)row * 1024 + tid * 4) = o;
}

// ---------------- launch ----------------
extern "C" void kernel_launch(void* const* d_in, const int* in_sizes, int n_in,
                              void* d_out, int out_size, void* d_ws, size_t ws_size,
                              hipStream_t stream) {
  const float* h    = (const float*)d_in[0];
  const float* r    = (const float*)d_in[1];
  const float* rwb  = (const float*)d_in[2];
  const float* rrb  = (const float*)d_in[3];
  const float* Wqkv = (const float*)d_in[4];
  const float* Wr   = (const float*)d_in[5];
  const float* Wo   = (const float*)d_in[6];
  const float* gam  = (const float*)d_in[7];
  const float* bet  = (const float*)d_in[8];
  float* out = (float*)d_out;

  u16* hb     = (u16*)d_ws;                          // 4096*1024
  u16* Wqkv_t = hb + (size_t)4096 * 1024;            // 3072*1024
  u16* Wr_t   = Wqkv_t + (size_t)3072 * 1024;        // 1024*1024
  u16* Wo_t   = Wr_t + (size_t)1024 * 1024;          // 1024*1024
  u16* rb     = Wo_t + (size_t)1024 * 1024;          // 2048*1024
  u16* qkv    = rb + (size_t)2048 * 1024;            // 4096*3072
  u16* rk     = qkv + (size_t)4096 * 3072;           // 2048*1024
  u16* vT     = rk + (size_t)2048 * 1024;            // 2*16*64*2048
  u16* av     = vT + (size_t)2 * 16 * 64 * 2048;     // 4096*1024
  float* tmp  = (float*)(av + (size_t)4096 * 1024);  // 4096*1024 f32

  k_cvt<<<4096, 256, 0, stream>>>(h, hb, 4096 * 1024 / 4);
  k_cvt<<<2048, 256, 0, stream>>>(r, rb, 2048 * 1024 / 4);
  k_tcvt<<<dim3(48, 16), 256, 0, stream>>>(Wqkv, Wqkv_t, 1024, 3072);
  k_tcvt<<<dim3(16, 16), 256, 0, stream>>>(Wr, Wr_t, 1024, 1024);
  k_tcvt<<<dim3(16, 16), 256, 0, stream>>>(Wo, Wo_t, 1024, 1024);
  k_gemm_bt<0><<<dim3(32, 24), 256, 0, stream>>>(hb, Wqkv_t, qkv, nullptr, nullptr,
                                                 4096, 3072, 1024);
  k_gemm_bt<0><<<dim3(16, 8), 256, 0, stream>>>(rb, Wr_t, rk, nullptr, nullptr,
                                                2048, 1024, 1024);
  k_vt<<<dim3(32, 32), 256, 0, stream>>>(qkv, vT);
  k_attn<<<1024, 256, 0, stream>>>(qkv, rk, vT, rwb, rrb, av);
  k_gemm_bt<1><<<dim3(32, 8), 256, 0, stream>>>(av, Wo_t, nullptr, tmp, h,
                                                4096, 1024, 1024);
  k_ln<<<4096, 256, 0, stream>>>(tmp, gam, bet, out);
}

// Round 18
// 259.364 us; speedup vs baseline: 1.0594x; 1.0594x over previous
//
#include <hip/hip_runtime.h>
#include <hip/hip_bf16.h>

typedef unsigned short u16;
typedef __attribute__((ext_vector_type(8))) short s16x8;
typedef __attribute__((ext_vector_type(8))) unsigned short u16x8;
typedef __attribute__((ext_vector_type(4))) float f32x4;

#define SEQ 2048
#define KEXP 0.18033688011112042f  /* 0.125 * log2(e) */

__device__ __forceinline__ float bf2f(u16 x) {
  union { unsigned u; float f; } c; c.u = ((unsigned)x) << 16; return c.f;
}
// hardware bf16 convert (v_cvt_pk_bf16_f32 on gfx950)
__device__ __forceinline__ u16 f2bf(float f) {
  __hip_bfloat16 h = __float2bfloat16(f);
  return __builtin_bit_cast(u16, h);
}
__device__ __forceinline__ unsigned pack2(float a, float b) {
  return (unsigned)f2bf(a) | ((unsigned)f2bf(b) << 16);
}
// async global->LDS, 16B per lane; LDS dest = wave-uniform base + lane*16
__device__ __forceinline__ void gload_lds16(const u16* g, u16* l) {
  __builtin_amdgcn_global_load_lds(
      (const __attribute__((address_space(1))) void*)g,
      (__attribute__((address_space(3))) void*)l, 16, 0, 0);
}

// ---------------- fp32 -> bf16 flat convert ----------------
__global__ __launch_bounds__(256) void k_cvt(const float* __restrict__ src,
                                             u16* __restrict__ dst, int n4) {
  int i = blockIdx.x * 256 + threadIdx.x;
  if (i >= n4) return;
  float4 v = ((const float4*)src)[i];
  ((ushort4*)dst)[i] = make_ushort4(f2bf(v.x), f2bf(v.y), f2bf(v.z), f2bf(v.w));
}

// ---------------- fp32 [R][C] -> bf16 [C][R] transpose-convert ----------------
__global__ __launch_bounds__(256) void k_tcvt(const float* __restrict__ src,
                                              u16* __restrict__ dst, int R, int C) {
  __shared__ u16 T[64][72];
  int r0 = blockIdx.y * 64, c0 = blockIdx.x * 64;
  int tid = threadIdx.x;
#pragma unroll
  for (int p = 0; p < 4; ++p) {
    int f = p * 256 + tid;            // float4 id within 64x64 tile
    int r = f >> 4, cc = (f & 15) * 4;
    float4 v = *(const float4*)(src + (size_t)(r0 + r) * C + c0 + cc);
    T[r][cc + 0] = f2bf(v.x); T[r][cc + 1] = f2bf(v.y);
    T[r][cc + 2] = f2bf(v.z); T[r][cc + 3] = f2bf(v.w);
  }
  __syncthreads();
#pragma unroll
  for (int p = 0; p < 2; ++p) {
    int f = p * 256 + tid;            // u16x8 chunk id
    int c = f >> 3, rr = (f & 7) * 8;
    u16x8 v;
#pragma unroll
    for (int e = 0; e < 8; ++e) v[e] = T[rr + e][c];
    *(u16x8*)(dst + (size_t)(c0 + c) * R + r0 + rr) = v;
  }
}

// ---------------- C[M,N] = A[M,K] @ Bt[N,K]^T  (bf16 in, bf16 or f32+res out) ----
// global_load_lds width=16 staging with BOTH-SIDES XOR swizzle (R16, proven):
// lane l loads global chunk (l&7)^(l>>3) -> LDS slot (r,c) holds global chunk
// c^r; fragment read at row R fetches chunk kc^(R&7) -> 2-way reads.
template <int RES>
__global__ __launch_bounds__(256) void k_gemm_bt(const u16* __restrict__ A,
                                                 const u16* __restrict__ Bt,
                                                 u16* __restrict__ Cb,
                                                 float* __restrict__ Cf,
                                                 const float* __restrict__ res,
                                                 int M, int N, int K) {
  __shared__ u16 As[128 * 64];
  __shared__ u16 Bs[128 * 64];
  const int tid = threadIdx.x;
  const int l = tid & 63, wv = tid >> 6;
  const int g = l >> 4, c16 = l & 15;
  const int m0 = blockIdx.x * 128, n0 = blockIdx.y * 128;
  const int wr = (wv >> 1) * 64, wc = (wv & 1) * 64;
  const int lrow = l >> 3;                 // 0..7 within 8-row slot
  const int lchunk = (l & 7) ^ lrow;       // pre-swizzled source chunk
  f32x4 acc[4][4] = {};
  for (int k0 = 0; k0 < K; k0 += 64) {
    __syncthreads();
    // 16 slots of 8 rows x 64 cols (1KB); wave wv owns slots 4wv..4wv+3
#pragma unroll
    for (int p = 0; p < 4; ++p) {
      int slot = wv * 4 + p;
      int row = slot * 8 + lrow;
      gload_lds16(A + (size_t)(m0 + row) * K + k0 + lchunk * 8, &As[slot * 512]);
      gload_lds16(Bt + (size_t)(n0 + row) * K + k0 + lchunk * 8, &Bs[slot * 512]);
    }
    __syncthreads();  // compiler drains vmcnt(0) before barrier
#pragma unroll
    for (int ks = 0; ks < 2; ++ks) {
      s16x8 af[4], bf[4];
      const int rc = c16 & 7;
#pragma unroll
      for (int fr = 0; fr < 4; ++fr)
        af[fr] = *(const s16x8*)&As[(wr + fr * 16 + c16) * 64 +
                                    (((ks * 4 + g) ^ rc) * 8)];
#pragma unroll
      for (int fc = 0; fc < 4; ++fc)
        bf[fc] = *(const s16x8*)&Bs[(wc + fc * 16 + c16) * 64 +
                                    (((ks * 4 + g) ^ rc) * 8)];
#pragma unroll
      for (int fr = 0; fr < 4; ++fr)
#pragma unroll
        for (int fc = 0; fc < 4; ++fc)
          acc[fr][fc] = __builtin_amdgcn_mfma_f32_16x16x32_bf16(af[fr], bf[fc],
                                                                acc[fr][fc], 0, 0, 0);
    }
  }
#pragma unroll
  for (int fr = 0; fr < 4; ++fr)
#pragma unroll
    for (int fc = 0; fc < 4; ++fc)
#pragma unroll
      for (int reg = 0; reg < 4; ++reg) {
        int row = m0 + wr + fr * 16 + g * 4 + reg;
        int col = n0 + wc + fc * 16 + c16;
        float v = acc[fr][fc][reg];
        if (RES) Cf[(size_t)row * N + col] = v + res[(size_t)row * N + col];
        else     Cb[(size_t)row * N + col] = f2bf(v);
      }
}

// ---------------- build V^T [b][n][d][j] from qkv ----------------
__global__ __launch_bounds__(256) void k_vt(const u16* __restrict__ qkv,
                                            u16* __restrict__ vT) {
  __shared__ u16 T[64][72];
  const int tid = threadIdx.x;
  const int j0 = blockIdx.x * 64;
  const int n = blockIdx.y & 15, b = blockIdx.y >> 4;
#pragma unroll
  for (int p = 0; p < 2; ++p) {
    int f = p * 256 + tid;
    int r = f >> 3, cc = (f & 7) * 8;
    *(u16x8*)&T[r][cc] =
        *(const u16x8*)(qkv + ((size_t)((j0 + r) * 2 + b)) * 3072 + 2048 + n * 64 + cc);
  }
  __syncthreads();
#pragma unroll
  for (int p = 0; p < 2; ++p) {
    int f = p * 256 + tid;
    int d = f >> 3, jc = (f & 7) * 8;
    u16x8 v;
#pragma unroll
    for (int e = 0; e < 8; ++e) v[e] = T[jc + e][d];
    *(u16x8*)(vT + ((size_t)((b * 16 + n) * 64 + d)) * 2048 + j0 + jc) = v;
  }
}

// ---------------- fused rel-attention (flash-style, KVBLK=128, swapped MFMA) ---
// R15/R16 exact (172.6 us, best verified): swapped-operand structure,
// write-address rel-shift bake, static-shift softmax (bounded scores),
// K/V/rk register prefetch under PV, setprio on MFMA clusters.
// KVBLK=64 (R17), LDS diets (R13/R14), de-staging (R13), T5-isolated (R12),
// and intra-iter micro-opts (R10) all measured neutral-or-negative:
// occupancy is pinned ~2 waves/SIMD by unified VGPR+acc allocation.
__global__ __launch_bounds__(256) void k_attn(const u16* __restrict__ qkv,
                                              const u16* __restrict__ rk,
                                              const u16* __restrict__ vT,
                                              const float* __restrict__ rwb,
                                              const float* __restrict__ rrb,
                                              u16* __restrict__ av) {
  __shared__ u16 Kt[128][72];    // K tile [j][d]
  __shared__ u16 Vt[64][136];    // V^T tile [d][j]
  __shared__ u16 St2[65 * 200];  // shifted band, physical row p = QR[p-1+delta]
  __shared__ u16 Pt[4][16][136]; // P strips, per wave [row=c16][jj]

  const int tid = threadIdx.x;
  const int l = tid & 63, wv = tid >> 6;
  const int g = l >> 4, c16 = l & 15;
  // XCD-aware swizzle: 4 consecutive bn per XCD -> K/V/rk L2-resident
  const int s = blockIdx.x;
  const int y = (s & 7) + 8 * (s >> 8);  // bn
  const int x = (s >> 3) & 31;           // i-tile
  const int i0 = x * 64;
  const int n = y & 15, b = y >> 4;
  const int ii = wv * 16 + c16;          // this lane's q-row (softmax domain)
  const f32x4 zero4 = {0.f, 0.f, 0.f, 0.f};
  const s16x8 zero8 = {0, 0, 0, 0, 0, 0, 0, 0};

  // ---- loop-invariant register fragments ----
  s16x8 qw[2];
  {
    int i = i0 + wv * 16 + c16;
    const u16* src = qkv + ((size_t)(i * 2 + b)) * 3072 + n * 64;
#pragma unroll
    for (int ks = 0; ks < 2; ++ks) {
      int d0 = ks * 32 + g * 8;
      u16x8 raw = *(const u16x8*)(src + d0);
      u16x8 wq;
#pragma unroll
      for (int e = 0; e < 8; ++e)
        wq[e] = f2bf(bf2f(raw[e]) + rwb[n * 64 + d0 + e]);
      qw[ks] = __builtin_bit_cast(s16x8, wq);
    }
  }
  s16x8 qr_b[4][2];
#pragma unroll
  for (int rb = 0; rb < 4; ++rb) {
    int i = i0 + rb * 16 + c16;
    const u16* src = qkv + ((size_t)(i * 2 + b)) * 3072 + n * 64;
#pragma unroll
    for (int ks = 0; ks < 2; ++ks) {
      int d0 = ks * 32 + g * 8;
      u16x8 raw = *(const u16x8*)(src + d0);
      u16x8 wq;
#pragma unroll
      for (int e = 0; e < 8; ++e)
        wq[e] = f2bf(bf2f(raw[e]) + rrb[n * 64 + d0 + e]);
      qr_b[rb][ks] = __builtin_bit_cast(s16x8, wq);
    }
  }
  s16x8 q64[2];
  {
    int i = i0 + 64; if (i > SEQ - 1) i = SEQ - 1;
    const u16* src = qkv + ((size_t)(i * 2 + b)) * 3072 + n * 64;
#pragma unroll
    for (int ks = 0; ks < 2; ++ks) {
      int d0 = ks * 32 + g * 8;
      u16x8 raw = *(const u16x8*)(src + d0);
      u16x8 wq;
#pragma unroll
      for (int e = 0; e < 8; ++e)
        wq[e] = f2bf(bf2f(raw[e]) + rrb[n * 64 + d0 + e]);
      q64[ks] = __builtin_bit_cast(s16x8, wq);
    }
  }

  // prefetch registers (issued during previous iteration's PV)
  u16x8 kpre[4], vpre[4];
  s16x8 rpre[3][2];
  auto issue_loads = [&](int j0n) {
#pragma unroll
    for (int p = 0; p < 4; ++p) {
      int f = p * 256 + tid;
      kpre[p] = *(const u16x8*)(qkv + ((size_t)((j0n + (f >> 3)) * 2 + b)) * 3072 +
                                1024 + n * 64 + (f & 7) * 8);
    }
#pragma unroll
    for (int p = 0; p < 4; ++p) {
      int f = p * 256 + tid;
      vpre[p] = *(const u16x8*)(vT + ((size_t)((b * 16 + n) * 64 + (f >> 4))) * 2048 +
                                j0n + (f & 15) * 8);
    }
#pragma unroll
    for (int c3 = 0; c3 < 3; ++c3) {
      int w = (wv * 3 + c3) * 16 + c16;
      int u = j0n - i0 - 63 + w;
      int c = (u <= 0) ? (u + (SEQ - 1)) : (u - 2);
      const u16* p = rk + (size_t)(c < 0 ? 0 : c) * 1024 + n * 64;
      rpre[c3][0] = *(const s16x8*)(p + g * 8);
      rpre[c3][1] = *(const s16x8*)(p + 32 + g * 8);
      if (c < 0) { rpre[c3][0] = zero8; rpre[c3][1] = zero8; }
    }
  };

  float l_sum = 0.f;
  f32x4 o_acc[4];
#pragma unroll
  for (int r = 0; r < 4; ++r) o_acc[r] = zero4;

  issue_loads(0);

  for (int it = 0; it < 16; ++it) {
    const int j0 = it * 128;
    const int wbthr = (64 + i0 - j0) >> 4;  // delta(wb) = (wb >= wbthr)
    __syncthreads();  // prev-iter St2/Kt/Vt reads complete

    // ds-write staged K/V (vmcnt hidden under previous PV)
#pragma unroll
    for (int p = 0; p < 4; ++p) {
      int f = p * 256 + tid;
      *(u16x8*)&Kt[f >> 3][(f & 7) * 8] = kpre[p];
    }
#pragma unroll
    for (int p = 0; p < 4; ++p) {
      int f = p * 256 + tid;
      *(u16x8*)&Vt[f >> 4][(f & 15) * 8] = vpre[p];
    }

    // QR_sw: D[w in regs][r in lanes]; rel-shift baked into WRITE ADDRESS:
    // physical row = r + 1 - delta(wb)  (wave-uniform offset, no dual frags)
#pragma unroll
    for (int c3 = 0; c3 < 3; ++c3) {
      const int wb = wv * 3 + c3;
      const int du = (wb >= wbthr) ? 1 : 0;  // wave-uniform
#pragma unroll
      for (int rb = 0; rb < 4; ++rb) {
        f32x4 q = zero4;
        q = __builtin_amdgcn_mfma_f32_16x16x32_bf16(rpre[c3][0], qr_b[rb][0], q, 0, 0, 0);
        q = __builtin_amdgcn_mfma_f32_16x16x32_bf16(rpre[c3][1], qr_b[rb][1], q, 0, 0, 0);
        uint2 pk;
        pk.x = pack2(q[0], q[1]);
        pk.y = pack2(q[2], q[3]);
        // row 0 (rb=0,c16=0,du=1) is the discard slot; rows 1..64 are live
        *(uint2*)&St2[(rb * 16 + c16 + 1 - du) * 200 + wb * 16 + g * 4] = pk;
      }
      // q64 extra row (QR[64][w]) -> physical row 64, only used where delta=1
      {
        f32x4 q = zero4;
        q = __builtin_amdgcn_mfma_f32_16x16x32_bf16(rpre[c3][0], q64[0], q, 0, 0, 0);
        q = __builtin_amdgcn_mfma_f32_16x16x32_bf16(rpre[c3][1], q64[1], q, 0, 0, 0);
        if (du && c16 == 0) {
          uint2 pk;
          pk.x = pack2(q[0], q[1]);
          pk.y = pack2(q[2], q[3]);
          *(uint2*)&St2[64 * 200 + wb * 16 + g * 4] = pk;
        }
      }
    }
    __syncthreads();  // Kt, Vt, St2 visible

    // AC_sw = mfma(K, Q): lane c16 = ii, regs = jj = fj*16 + g*4 + reg
    f32x4 sc[8];
#pragma unroll
    for (int fj = 0; fj < 8; ++fj) sc[fj] = zero4;
    __builtin_amdgcn_s_setprio(1);
#pragma unroll
    for (int ks = 0; ks < 2; ++ks)
#pragma unroll
      for (int fj = 0; fj < 8; ++fj) {
        s16x8 kf = *(const s16x8*)&Kt[fj * 16 + c16][ks * 32 + g * 8];
        sc[fj] = __builtin_amdgcn_mfma_f32_16x16x32_bf16(kf, qw[ks], sc[fj], 0, 0, 0);
      }
    __builtin_amdgcn_s_setprio(0);

    // gather BD: physical row ii+1, col w = jj-ii+63
    // offset = (ii+1)*200 + jj - ii + 63 = ii*199 + 263 + fj*16 + g*4 + reg
    {
      const u16* Sb = &St2[ii * 199 + 263 + g * 4];
#pragma unroll
      for (int fj = 0; fj < 8; ++fj)
#pragma unroll
        for (int reg = 0; reg < 4; ++reg)
          sc[fj][reg] += bf2f(Sb[fj * 16 + reg]);
    }

    // static-shift softmax: p = exp2(s * KEXP) directly (bounded scores)
    float rs = 0.f;
#pragma unroll
    for (int fj = 0; fj < 8; ++fj)
#pragma unroll
      for (int reg = 0; reg < 4; ++reg) {
        float p = __builtin_amdgcn_exp2f(sc[fj][reg] * KEXP);
        rs += p;
        sc[fj][reg] = p;  // reuse sc as P
      }
    rs += __shfl_xor(rs, 16);
    rs += __shfl_xor(rs, 32);
    l_sum += rs;

    // P -> own strip (aligned b64), then read back as A-frags (same wave)
#pragma unroll
    for (int fj = 0; fj < 8; ++fj) {
      uint2 pk;
      pk.x = pack2(sc[fj][0], sc[fj][1]);
      pk.y = pack2(sc[fj][2], sc[fj][3]);
      *(uint2*)&Pt[wv][c16][fj * 16 + g * 4] = pk;
    }

    // prefetch next tile's K/V/rk while PV runs
    if (it < 15) issue_loads(j0 + 128);

    // PV: O += P @ V (A = P strip, row = c16 = ii)
    __builtin_amdgcn_s_setprio(1);
#pragma unroll
    for (int ks = 0; ks < 4; ++ks) {
      s16x8 pa = *(const s16x8*)&Pt[wv][c16][ks * 32 + g * 8];
#pragma unroll
      for (int fd = 0; fd < 4; ++fd) {
        s16x8 vb = *(const s16x8*)&Vt[fd * 16 + c16][ks * 32 + g * 8];
        o_acc[fd] = __builtin_amdgcn_mfma_f32_16x16x32_bf16(pa, vb, o_acc[fd], 0, 0, 0);
      }
    }
    __builtin_amdgcn_s_setprio(0);
  }

  // epilogue: transpose 1/l across lanes (rows in reg-dim)
  float linv = 1.0f / l_sum;
  float linv_t[4];
#pragma unroll
  for (int reg = 0; reg < 4; ++reg)
    linv_t[reg] = __shfl(linv, g * 4 + reg, 64);
#pragma unroll
  for (int reg = 0; reg < 4; ++reg) {
    int i = i0 + wv * 16 + g * 4 + reg;
    u16* dst = av + ((size_t)(i * 2 + b)) * 1024 + n * 64;
#pragma unroll
    for (int fd = 0; fd < 4; ++fd)
      dst[fd * 16 + c16] = f2bf(o_acc[fd][reg] * linv_t[reg]);
  }
}

// ---------------- LayerNorm over rows of tmp (= attn_out + h) ----------------
__global__ __launch_bounds__(256) void k_ln(const float* __restrict__ tmp,
                                            const float* __restrict__ gamma,
                                            const float* __restrict__ beta,
                                            float* __restrict__ out) {
  __shared__ float r1[4], r2[4];
  const int row = blockIdx.x, tid = threadIdx.x;
  const float* x = tmp + (size_t)row * 1024;
  float4 v = *(const float4*)(x + tid * 4);
  float s1 = v.x + v.y + v.z + v.w;
  float s2 = v.x * v.x + v.y * v.y + v.z * v.z + v.w * v.w;
#pragma unroll
  for (int off = 1; off < 64; off <<= 1) {
    s1 += __shfl_xor(s1, off, 64);
    s2 += __shfl_xor(s2, off, 64);
  }
  if ((tid & 63) == 0) { r1[tid >> 6] = s1; r2[tid >> 6] = s2; }
  __syncthreads();
  s1 = r1[0] + r1[1] + r1[2] + r1[3];
  s2 = r2[0] + r2[1] + r2[2] + r2[3];
  float mu = s1 * (1.f / 1024.f);
  float var = s2 * (1.f / 1024.f) - mu * mu;
  float rstd = rsqrtf(var + 1e-6f);
  float4 gm = *(const float4*)(gamma + tid * 4);
  float4 bt = *(const float4*)(beta + tid * 4);
  float4 o;
  o.x = (v.x - mu) * rstd * gm.x + bt.x;
  o.y = (v.y - mu) * rstd * gm.y + bt.y;
  o.z = (v.z - mu) * rstd * gm.z + bt.z;
  o.w = (v.w - mu) * rstd * gm.w + bt.w;
  *(float4*)(out + (size_t)row * 1024 + tid * 4) = o;
}

// ---------------- launch ----------------
extern "C" void kernel_launch(void* const* d_in, const int* in_sizes, int n_in,
                              void* d_out, int out_size, void* d_ws, size_t ws_size,
                              hipStream_t stream) {
  const float* h    = (const float*)d_in[0];
  const float* r    = (const float*)d_in[1];
  const float* rwb  = (const float*)d_in[2];
  const float* rrb  = (const float*)d_in[3];
  const float* Wqkv = (const float*)d_in[4];
  const float* Wr   = (const float*)d_in[5];
  const float* Wo   = (const float*)d_in[6];
  const float* gam  = (const float*)d_in[7];
  const float* bet  = (const float*)d_in[8];
  float* out = (float*)d_out;

  u16* hb     = (u16*)d_ws;                          // 4096*1024
  u16* Wqkv_t = hb + (size_t)4096 * 1024;            // 3072*1024
  u16* Wr_t   = Wqkv_t + (size_t)3072 * 1024;        // 1024*1024
  u16* Wo_t   = Wr_t + (size_t)1024 * 1024;          // 1024*1024
  u16* rb     = Wo_t + (size_t)1024 * 1024;          // 2048*1024
  u16* qkv    = rb + (size_t)2048 * 1024;            // 4096*3072
  u16* rk     = qkv + (size_t)4096 * 3072;           // 2048*1024
  u16* vT     = rk + (size_t)2048 * 1024;            // 2*16*64*2048
  u16* av     = vT + (size_t)2 * 16 * 64 * 2048;     // 4096*1024
  float* tmp  = (float*)(av + (size_t)4096 * 1024);  // 4096*1024 f32

  k_cvt<<<4096, 256, 0, stream>>>(h, hb, 4096 * 1024 / 4);
  k_cvt<<<2048, 256, 0, stream>>>(r, rb, 2048 * 1024 / 4);
  k_tcvt<<<dim3(48, 16), 256, 0, stream>>>(Wqkv, Wqkv_t, 1024, 3072);
  k_tcvt<<<dim3(16, 16), 256, 0, stream>>>(Wr, Wr_t, 1024, 1024);
  k_tcvt<<<dim3(16, 16), 256, 0, stream>>>(Wo, Wo_t, 1024, 1024);
  k_gemm_bt<0><<<dim3(32, 24), 256, 0, stream>>>(hb, Wqkv_t, qkv, nullptr, nullptr,
                                                 4096, 3072, 1024);
  k_gemm_bt<0><<<dim3(16, 8), 256, 0, stream>>>(rb, Wr_t, rk, nullptr, nullptr,
                                                2048, 1024, 1024);
  k_vt<<<dim3(32, 32), 256, 0, stream>>>(qkv, vT);
  k_attn<<<1024, 256, 0, stream>>>(qkv, rk, vT, rwb, rrb, av);
  k_gemm_bt<1><<<dim3(32, 8), 256, 0, stream>>>(av, Wo_t, nullptr, tmp, h,
                                                4096, 1024, 1024);
  k_ln<<<4096, 256, 0, stream>>>(tmp, gam, bet, out);
}

// Round 19
// 253.341 us; speedup vs baseline: 1.0846x; 1.0238x over previous
//
#include <hip/hip_runtime.h>
#include <hip/hip_bf16.h>

typedef unsigned short u16;
typedef __attribute__((ext_vector_type(8))) short s16x8;
typedef __attribute__((ext_vector_type(8))) unsigned short u16x8;
typedef __attribute__((ext_vector_type(4))) float f32x4;

#define SEQ 2048
#define KEXP 0.18033688011112042f  /* 0.125 * log2(e) */

__device__ __forceinline__ float bf2f(u16 x) {
  union { unsigned u; float f; } c; c.u = ((unsigned)x) << 16; return c.f;
}
// hardware bf16 convert (v_cvt_pk_bf16_f32 on gfx950)
__device__ __forceinline__ u16 f2bf(float f) {
  __hip_bfloat16 h = __float2bfloat16(f);
  return __builtin_bit_cast(u16, h);
}
__device__ __forceinline__ unsigned pack2(float a, float b) {
  return (unsigned)f2bf(a) | ((unsigned)f2bf(b) << 16);
}
// async global->LDS, 16B per lane; LDS dest = wave-uniform base + lane*16
__device__ __forceinline__ void gload_lds16(const u16* g, u16* l) {
  __builtin_amdgcn_global_load_lds(
      (const __attribute__((address_space(1))) void*)g,
      (__attribute__((address_space(3))) void*)l, 16, 0, 0);
}

// ---------------- merged fp32 -> bf16 flat converts (h then r) ----------------
__global__ __launch_bounds__(256) void k_cvt2(const float* __restrict__ a,
                                              u16* __restrict__ da, int n4a,
                                              const float* __restrict__ b2,
                                              u16* __restrict__ db, int n4b) {
  int i = blockIdx.x * 256 + threadIdx.x;
  if (i < n4a) {
    float4 v = ((const float4*)a)[i];
    ((ushort4*)da)[i] = make_ushort4(f2bf(v.x), f2bf(v.y), f2bf(v.z), f2bf(v.w));
  } else {
    int j = i - n4a;
    if (j < n4b) {
      float4 v = ((const float4*)b2)[j];
      ((ushort4*)db)[j] = make_ushort4(f2bf(v.x), f2bf(v.y), f2bf(v.z), f2bf(v.w));
    }
  }
}

// ---------- merged fp32 [1024][C] -> bf16 [C][1024] transpose-converts --------
// blockIdx.x ranges: [0,48) Wqkv (C=3072), [48,64) Wr (C=1024), [64,80) Wo.
__global__ __launch_bounds__(256) void k_tcvt3(const float* __restrict__ Wqkv,
                                               u16* __restrict__ Wqkv_t,
                                               const float* __restrict__ Wr,
                                               u16* __restrict__ Wr_t,
                                               const float* __restrict__ Wo,
                                               u16* __restrict__ Wo_t) {
  const float* src; u16* dst; int C, cx;
  int bx = blockIdx.x;
  if (bx < 48)      { src = Wqkv; dst = Wqkv_t; C = 3072; cx = bx; }
  else if (bx < 64) { src = Wr;   dst = Wr_t;   C = 1024; cx = bx - 48; }
  else              { src = Wo;   dst = Wo_t;   C = 1024; cx = bx - 64; }
  const int R = 1024;
  __shared__ u16 T[64][72];
  int r0 = blockIdx.y * 64, c0 = cx * 64;
  int tid = threadIdx.x;
#pragma unroll
  for (int p = 0; p < 4; ++p) {
    int f = p * 256 + tid;            // float4 id within 64x64 tile
    int r = f >> 4, cc = (f & 15) * 4;
    float4 v = *(const float4*)(src + (size_t)(r0 + r) * C + c0 + cc);
    T[r][cc + 0] = f2bf(v.x); T[r][cc + 1] = f2bf(v.y);
    T[r][cc + 2] = f2bf(v.z); T[r][cc + 3] = f2bf(v.w);
  }
  __syncthreads();
#pragma unroll
  for (int p = 0; p < 2; ++p) {
    int f = p * 256 + tid;            // u16x8 chunk id
    int c = f >> 3, rr = (f & 7) * 8;
    u16x8 v;
#pragma unroll
    for (int e = 0; e < 8; ++e) v[e] = T[rr + e][c];
    *(u16x8*)(dst + (size_t)(c0 + c) * R + r0 + rr) = v;
  }
}

// ---------------- C[M,N] = A[M,K] @ Bt[N,K]^T  (bf16 in, bf16 or f32+res out) ----
// global_load_lds width=16 staging with BOTH-SIDES XOR swizzle (R16, proven):
// lane l loads global chunk (l&7)^(l>>3) -> LDS slot (r,c) holds global chunk
// c^r; fragment read at row R fetches chunk kc^(R&7) -> 2-way reads.
template <int RES>
__global__ __launch_bounds__(256) void k_gemm_bt(const u16* __restrict__ A,
                                                 const u16* __restrict__ Bt,
                                                 u16* __restrict__ Cb,
                                                 float* __restrict__ Cf,
                                                 const float* __restrict__ res,
                                                 int M, int N, int K) {
  __shared__ u16 As[128 * 64];
  __shared__ u16 Bs[128 * 64];
  const int tid = threadIdx.x;
  const int l = tid & 63, wv = tid >> 6;
  const int g = l >> 4, c16 = l & 15;
  const int m0 = blockIdx.x * 128, n0 = blockIdx.y * 128;
  const int wr = (wv >> 1) * 64, wc = (wv & 1) * 64;
  const int lrow = l >> 3;                 // 0..7 within 8-row slot
  const int lchunk = (l & 7) ^ lrow;       // pre-swizzled source chunk
  f32x4 acc[4][4] = {};
  for (int k0 = 0; k0 < K; k0 += 64) {
    __syncthreads();
    // 16 slots of 8 rows x 64 cols (1KB); wave wv owns slots 4wv..4wv+3
#pragma unroll
    for (int p = 0; p < 4; ++p) {
      int slot = wv * 4 + p;
      int row = slot * 8 + lrow;
      gload_lds16(A + (size_t)(m0 + row) * K + k0 + lchunk * 8, &As[slot * 512]);
      gload_lds16(Bt + (size_t)(n0 + row) * K + k0 + lchunk * 8, &Bs[slot * 512]);
    }
    __syncthreads();  // compiler drains vmcnt(0) before barrier
#pragma unroll
    for (int ks = 0; ks < 2; ++ks) {
      s16x8 af[4], bf[4];
      const int rc = c16 & 7;
#pragma unroll
      for (int fr = 0; fr < 4; ++fr)
        af[fr] = *(const s16x8*)&As[(wr + fr * 16 + c16) * 64 +
                                    (((ks * 4 + g) ^ rc) * 8)];
#pragma unroll
      for (int fc = 0; fc < 4; ++fc)
        bf[fc] = *(const s16x8*)&Bs[(wc + fc * 16 + c16) * 64 +
                                    (((ks * 4 + g) ^ rc) * 8)];
#pragma unroll
      for (int fr = 0; fr < 4; ++fr)
#pragma unroll
        for (int fc = 0; fc < 4; ++fc)
          acc[fr][fc] = __builtin_amdgcn_mfma_f32_16x16x32_bf16(af[fr], bf[fc],
                                                                acc[fr][fc], 0, 0, 0);
    }
  }
#pragma unroll
  for (int fr = 0; fr < 4; ++fr)
#pragma unroll
    for (int fc = 0; fc < 4; ++fc)
#pragma unroll
      for (int reg = 0; reg < 4; ++reg) {
        int row = m0 + wr + fr * 16 + g * 4 + reg;
        int col = n0 + wc + fc * 16 + c16;
        float v = acc[fr][fc][reg];
        if (RES) Cf[(size_t)row * N + col] = v + res[(size_t)row * N + col];
        else     Cb[(size_t)row * N + col] = f2bf(v);
      }
}

// ---------------- build V^T [b][n][d][j] from qkv ----------------
__global__ __launch_bounds__(256) void k_vt(const u16* __restrict__ qkv,
                                            u16* __restrict__ vT) {
  __shared__ u16 T[64][72];
  const int tid = threadIdx.x;
  const int j0 = blockIdx.x * 64;
  const int n = blockIdx.y & 15, b = blockIdx.y >> 4;
#pragma unroll
  for (int p = 0; p < 2; ++p) {
    int f = p * 256 + tid;
    int r = f >> 3, cc = (f & 7) * 8;
    *(u16x8*)&T[r][cc] =
        *(const u16x8*)(qkv + ((size_t)((j0 + r) * 2 + b)) * 3072 + 2048 + n * 64 + cc);
  }
  __syncthreads();
#pragma unroll
  for (int p = 0; p < 2; ++p) {
    int f = p * 256 + tid;
    int d = f >> 3, jc = (f & 7) * 8;
    u16x8 v;
#pragma unroll
    for (int e = 0; e < 8; ++e) v[e] = T[jc + e][d];
    *(u16x8*)(vT + ((size_t)((b * 16 + n) * 64 + d)) * 2048 + j0 + jc) = v;
  }
}

// ---------------- fused rel-attention (flash-style, KVBLK=128, swapped MFMA) ---
// R15/R16/R18 exact (172.5 us, best verified): swapped-operand structure,
// write-address rel-shift bake, static-shift softmax (bounded scores),
// K/V/rk register prefetch under PV, setprio on MFMA clusters.
__global__ __launch_bounds__(256) void k_attn(const u16* __restrict__ qkv,
                                              const u16* __restrict__ rk,
                                              const u16* __restrict__ vT,
                                              const float* __restrict__ rwb,
                                              const float* __restrict__ rrb,
                                              u16* __restrict__ av) {
  __shared__ u16 Kt[128][72];    // K tile [j][d]
  __shared__ u16 Vt[64][136];    // V^T tile [d][j]
  __shared__ u16 St2[65 * 200];  // shifted band, physical row p = QR[p-1+delta]
  __shared__ u16 Pt[4][16][136]; // P strips, per wave [row=c16][jj]

  const int tid = threadIdx.x;
  const int l = tid & 63, wv = tid >> 6;
  const int g = l >> 4, c16 = l & 15;
  // XCD-aware swizzle: 4 consecutive bn per XCD -> K/V/rk L2-resident
  const int s = blockIdx.x;
  const int y = (s & 7) + 8 * (s >> 8);  // bn
  const int x = (s >> 3) & 31;           // i-tile
  const int i0 = x * 64;
  const int n = y & 15, b = y >> 4;
  const int ii = wv * 16 + c16;          // this lane's q-row (softmax domain)
  const f32x4 zero4 = {0.f, 0.f, 0.f, 0.f};
  const s16x8 zero8 = {0, 0, 0, 0, 0, 0, 0, 0};

  // ---- loop-invariant register fragments ----
  s16x8 qw[2];
  {
    int i = i0 + wv * 16 + c16;
    const u16* src = qkv + ((size_t)(i * 2 + b)) * 3072 + n * 64;
#pragma unroll
    for (int ks = 0; ks < 2; ++ks) {
      int d0 = ks * 32 + g * 8;
      u16x8 raw = *(const u16x8*)(src + d0);
      u16x8 wq;
#pragma unroll
      for (int e = 0; e < 8; ++e)
        wq[e] = f2bf(bf2f(raw[e]) + rwb[n * 64 + d0 + e]);
      qw[ks] = __builtin_bit_cast(s16x8, wq);
    }
  }
  s16x8 qr_b[4][2];
#pragma unroll
  for (int rb = 0; rb < 4; ++rb) {
    int i = i0 + rb * 16 + c16;
    const u16* src = qkv + ((size_t)(i * 2 + b)) * 3072 + n * 64;
#pragma unroll
    for (int ks = 0; ks < 2; ++ks) {
      int d0 = ks * 32 + g * 8;
      u16x8 raw = *(const u16x8*)(src + d0);
      u16x8 wq;
#pragma unroll
      for (int e = 0; e < 8; ++e)
        wq[e] = f2bf(bf2f(raw[e]) + rrb[n * 64 + d0 + e]);
      qr_b[rb][ks] = __builtin_bit_cast(s16x8, wq);
    }
  }
  s16x8 q64[2];
  {
    int i = i0 + 64; if (i > SEQ - 1) i = SEQ - 1;
    const u16* src = qkv + ((size_t)(i * 2 + b)) * 3072 + n * 64;
#pragma unroll
    for (int ks = 0; ks < 2; ++ks) {
      int d0 = ks * 32 + g * 8;
      u16x8 raw = *(const u16x8*)(src + d0);
      u16x8 wq;
#pragma unroll
      for (int e = 0; e < 8; ++e)
        wq[e] = f2bf(bf2f(raw[e]) + rrb[n * 64 + d0 + e]);
      q64[ks] = __builtin_bit_cast(s16x8, wq);
    }
  }

  // prefetch registers (issued during previous iteration's PV)
  u16x8 kpre[4], vpre[4];
  s16x8 rpre[3][2];
  auto issue_loads = [&](int j0n) {
#pragma unroll
    for (int p = 0; p < 4; ++p) {
      int f = p * 256 + tid;
      kpre[p] = *(const u16x8*)(qkv + ((size_t)((j0n + (f >> 3)) * 2 + b)) * 3072 +
                                1024 + n * 64 + (f & 7) * 8);
    }
#pragma unroll
    for (int p = 0; p < 4; ++p) {
      int f = p * 256 + tid;
      vpre[p] = *(const u16x8*)(vT + ((size_t)((b * 16 + n) * 64 + (f >> 4))) * 2048 +
                                j0n + (f & 15) * 8);
    }
#pragma unroll
    for (int c3 = 0; c3 < 3; ++c3) {
      int w = (wv * 3 + c3) * 16 + c16;
      int u = j0n - i0 - 63 + w;
      int c = (u <= 0) ? (u + (SEQ - 1)) : (u - 2);
      const u16* p = rk + (size_t)(c < 0 ? 0 : c) * 1024 + n * 64;
      rpre[c3][0] = *(const s16x8*)(p + g * 8);
      rpre[c3][1] = *(const s16x8*)(p + 32 + g * 8);
      if (c < 0) { rpre[c3][0] = zero8; rpre[c3][1] = zero8; }
    }
  };

  float l_sum = 0.f;
  f32x4 o_acc[4];
#pragma unroll
  for (int r = 0; r < 4; ++r) o_acc[r] = zero4;

  issue_loads(0);

  for (int it = 0; it < 16; ++it) {
    const int j0 = it * 128;
    const int wbthr = (64 + i0 - j0) >> 4;  // delta(wb) = (wb >= wbthr)
    __syncthreads();  // prev-iter St2/Kt/Vt reads complete

    // ds-write staged K/V (vmcnt hidden under previous PV)
#pragma unroll
    for (int p = 0; p < 4; ++p) {
      int f = p * 256 + tid;
      *(u16x8*)&Kt[f >> 3][(f & 7) * 8] = kpre[p];
    }
#pragma unroll
    for (int p = 0; p < 4; ++p) {
      int f = p * 256 + tid;
      *(u16x8*)&Vt[f >> 4][(f & 15) * 8] = vpre[p];
    }

    // QR_sw: D[w in regs][r in lanes]; rel-shift baked into WRITE ADDRESS:
    // physical row = r + 1 - delta(wb)  (wave-uniform offset, no dual frags)
#pragma unroll
    for (int c3 = 0; c3 < 3; ++c3) {
      const int wb = wv * 3 + c3;
      const int du = (wb >= wbthr) ? 1 : 0;  // wave-uniform
#pragma unroll
      for (int rb = 0; rb < 4; ++rb) {
        f32x4 q = zero4;
        q = __builtin_amdgcn_mfma_f32_16x16x32_bf16(rpre[c3][0], qr_b[rb][0], q, 0, 0, 0);
        q = __builtin_amdgcn_mfma_f32_16x16x32_bf16(rpre[c3][1], qr_b[rb][1], q, 0, 0, 0);
        uint2 pk;
        pk.x = pack2(q[0], q[1]);
        pk.y = pack2(q[2], q[3]);
        // row 0 (rb=0,c16=0,du=1) is the discard slot; rows 1..64 are live
        *(uint2*)&St2[(rb * 16 + c16 + 1 - du) * 200 + wb * 16 + g * 4] = pk;
      }
      // q64 extra row (QR[64][w]) -> physical row 64, only used where delta=1
      {
        f32x4 q = zero4;
        q = __builtin_amdgcn_mfma_f32_16x16x32_bf16(rpre[c3][0], q64[0], q, 0, 0, 0);
        q = __builtin_amdgcn_mfma_f32_16x16x32_bf16(rpre[c3][1], q64[1], q, 0, 0, 0);
        if (du && c16 == 0) {
          uint2 pk;
          pk.x = pack2(q[0], q[1]);
          pk.y = pack2(q[2], q[3]);
          *(uint2*)&St2[64 * 200 + wb * 16 + g * 4] = pk;
        }
      }
    }
    __syncthreads();  // Kt, Vt, St2 visible

    // AC_sw = mfma(K, Q): lane c16 = ii, regs = jj = fj*16 + g*4 + reg
    f32x4 sc[8];
#pragma unroll
    for (int fj = 0; fj < 8; ++fj) sc[fj] = zero4;
    __builtin_amdgcn_s_setprio(1);
#pragma unroll
    for (int ks = 0; ks < 2; ++ks)
#pragma unroll
      for (int fj = 0; fj < 8; ++fj) {
        s16x8 kf = *(const s16x8*)&Kt[fj * 16 + c16][ks * 32 + g * 8];
        sc[fj] = __builtin_amdgcn_mfma_f32_16x16x32_bf16(kf, qw[ks], sc[fj], 0, 0, 0);
      }
    __builtin_amdgcn_s_setprio(0);

    // gather BD: physical row ii+1, col w = jj-ii+63
    // offset = (ii+1)*200 + jj - ii + 63 = ii*199 + 263 + fj*16 + g*4 + reg
    {
      const u16* Sb = &St2[ii * 199 + 263 + g * 4];
#pragma unroll
      for (int fj = 0; fj < 8; ++fj)
#pragma unroll
        for (int reg = 0; reg < 4; ++reg)
          sc[fj][reg] += bf2f(Sb[fj * 16 + reg]);
    }

    // static-shift softmax: p = exp2(s * KEXP) directly (bounded scores)
    float rs = 0.f;
#pragma unroll
    for (int fj = 0; fj < 8; ++fj)
#pragma unroll
      for (int reg = 0; reg < 4; ++reg) {
        float p = __builtin_amdgcn_exp2f(sc[fj][reg] * KEXP);
        rs += p;
        sc[fj][reg] = p;  // reuse sc as P
      }
    rs += __shfl_xor(rs, 16);
    rs += __shfl_xor(rs, 32);
    l_sum += rs;

    // P -> own strip (aligned b64), then read back as A-frags (same wave)
#pragma unroll
    for (int fj = 0; fj < 8; ++fj) {
      uint2 pk;
      pk.x = pack2(sc[fj][0], sc[fj][1]);
      pk.y = pack2(sc[fj][2], sc[fj][3]);
      *(uint2*)&Pt[wv][c16][fj * 16 + g * 4] = pk;
    }

    // prefetch next tile's K/V/rk while PV runs
    if (it < 15) issue_loads(j0 + 128);

    // PV: O += P @ V (A = P strip, row = c16 = ii)
    __builtin_amdgcn_s_setprio(1);
#pragma unroll
    for (int ks = 0; ks < 4; ++ks) {
      s16x8 pa = *(const s16x8*)&Pt[wv][c16][ks * 32 + g * 8];
#pragma unroll
      for (int fd = 0; fd < 4; ++fd) {
        s16x8 vb = *(const s16x8*)&Vt[fd * 16 + c16][ks * 32 + g * 8];
        o_acc[fd] = __builtin_amdgcn_mfma_f32_16x16x32_bf16(pa, vb, o_acc[fd], 0, 0, 0);
      }
    }
    __builtin_amdgcn_s_setprio(0);
  }

  // epilogue: transpose 1/l across lanes (rows in reg-dim)
  float linv = 1.0f / l_sum;
  float linv_t[4];
#pragma unroll
  for (int reg = 0; reg < 4; ++reg)
    linv_t[reg] = __shfl(linv, g * 4 + reg, 64);
#pragma unroll
  for (int reg = 0; reg < 4; ++reg) {
    int i = i0 + wv * 16 + g * 4 + reg;
    u16* dst = av + ((size_t)(i * 2 + b)) * 1024 + n * 64;
#pragma unroll
    for (int fd = 0; fd < 4; ++fd)
      dst[fd * 16 + c16] = f2bf(o_acc[fd][reg] * linv_t[reg]);
  }
}

// ---------------- LayerNorm over rows of tmp (= attn_out + h) ----------------
__global__ __launch_bounds__(256) void k_ln(const float* __restrict__ tmp,
                                            const float* __restrict__ gamma,
                                            const float* __restrict__ beta,
                                            float* __restrict__ out) {
  __shared__ float r1[4], r2[4];
  const int row = blockIdx.x, tid = threadIdx.x;
  const float* x = tmp + (size_t)row * 1024;
  float4 v = *(const float4*)(x + tid * 4);
  float s1 = v.x + v.y + v.z + v.w;
  float s2 = v.x * v.x + v.y * v.y + v.z * v.z + v.w * v.w;
#pragma unroll
  for (int off = 1; off < 64; off <<= 1) {
    s1 += __shfl_xor(s1, off, 64);
    s2 += __shfl_xor(s2, off, 64);
  }
  if ((tid & 63) == 0) { r1[tid >> 6] = s1; r2[tid >> 6] = s2; }
  __syncthreads();
  s1 = r1[0] + r1[1] + r1[2] + r1[3];
  s2 = r2[0] + r2[1] + r2[2] + r2[3];
  float mu = s1 * (1.f / 1024.f);
  float var = s2 * (1.f / 1024.f) - mu * mu;
  float rstd = rsqrtf(var + 1e-6f);
  float4 gm = *(const float4*)(gamma + tid * 4);
  float4 bt = *(const float4*)(beta + tid * 4);
  float4 o;
  o.x = (v.x - mu) * rstd * gm.x + bt.x;
  o.y = (v.y - mu) * rstd * gm.y + bt.y;
  o.z = (v.z - mu) * rstd * gm.z + bt.z;
  o.w = (v.w - mu) * rstd * gm.w + bt.w;
  *(float4*)(out + (size_t)row * 1024 + tid * 4) = o;
}

// ---------------- launch ----------------
extern "C" void kernel_launch(void* const* d_in, const int* in_sizes, int n_in,
                              void* d_out, int out_size, void* d_ws, size_t ws_size,
                              hipStream_t stream) {
  const float* h    = (const float*)d_in[0];
  const float* r    = (const float*)d_in[1];
  const float* rwb  = (const float*)d_in[2];
  const float* rrb  = (const float*)d_in[3];
  const float* Wqkv = (const float*)d_in[4];
  const float* Wr   = (const float*)d_in[5];
  const float* Wo   = (const float*)d_in[6];
  const float* gam  = (const float*)d_in[7];
  const float* bet  = (const float*)d_in[8];
  float* out = (float*)d_out;

  u16* hb     = (u16*)d_ws;                          // 4096*1024
  u16* Wqkv_t = hb + (size_t)4096 * 1024;            // 3072*1024
  u16* Wr_t   = Wqkv_t + (size_t)3072 * 1024;        // 1024*1024
  u16* Wo_t   = Wr_t + (size_t)1024 * 1024;          // 1024*1024
  u16* rb     = Wo_t + (size_t)1024 * 1024;          // 2048*1024
  u16* qkv    = rb + (size_t)2048 * 1024;            // 4096*3072
  u16* rk     = qkv + (size_t)4096 * 3072;           // 2048*1024
  u16* vT     = rk + (size_t)2048 * 1024;            // 2*16*64*2048
  u16* av     = vT + (size_t)2 * 16 * 64 * 2048;     // 4096*1024
  float* tmp  = (float*)(av + (size_t)4096 * 1024);  // 4096*1024 f32

  k_cvt2<<<6144, 256, 0, stream>>>(h, hb, 4096 * 1024 / 4, r, rb, 2048 * 1024 / 4);
  k_tcvt3<<<dim3(80, 16), 256, 0, stream>>>(Wqkv, Wqkv_t, Wr, Wr_t, Wo, Wo_t);
  k_gemm_bt<0><<<dim3(32, 24), 256, 0, stream>>>(hb, Wqkv_t, qkv, nullptr, nullptr,
                                                 4096, 3072, 1024);
  k_gemm_bt<0><<<dim3(16, 8), 256, 0, stream>>>(rb, Wr_t, rk, nullptr, nullptr,
                                                2048, 1024, 1024);
  k_vt<<<dim3(32, 32), 256, 0, stream>>>(qkv, vT);
  k_attn<<<1024, 256, 0, stream>>>(qkv, rk, vT, rwb, rrb, av);
  k_gemm_bt<1><<<dim3(32, 8), 256, 0, stream>>>(av, Wo_t, nullptr, tmp, h,
                                                4096, 1024, 1024);
  k_ln<<<4096, 256, 0, stream>>>(tmp, gam, bet, out);
}

// Round 20
// 245.088 us; speedup vs baseline: 1.1211x; 1.0337x over previous
//
#include <hip/hip_runtime.h>
#include <hip/hip_bf16.h>

typedef unsigned short u16;
typedef __attribute__((ext_vector_type(8))) short s16x8;
typedef __attribute__((ext_vector_type(8))) unsigned short u16x8;
typedef __attribute__((ext_vector_type(4))) float f32x4;

#define SEQ 2048
#define KEXP 0.18033688011112042f  /* 0.125 * log2(e) */

__device__ __forceinline__ float bf2f(u16 x) {
  union { unsigned u; float f; } c; c.u = ((unsigned)x) << 16; return c.f;
}
// hardware bf16 convert (v_cvt_pk_bf16_f32 on gfx950)
__device__ __forceinline__ u16 f2bf(float f) {
  __hip_bfloat16 h = __float2bfloat16(f);
  return __builtin_bit_cast(u16, h);
}
__device__ __forceinline__ unsigned pack2(float a, float b) {
  return (unsigned)f2bf(a) | ((unsigned)f2bf(b) << 16);
}
// async global->LDS, 16B per lane; LDS dest = wave-uniform base + lane*16
__device__ __forceinline__ void gload_lds16(const u16* g, u16* l) {
  __builtin_amdgcn_global_load_lds(
      (const __attribute__((address_space(1))) void*)g,
      (__attribute__((address_space(3))) void*)l, 16, 0, 0);
}

// ---------------- merged prologue: flat converts + weight transposes ----------
// blocks [0,6144): fp32->bf16 flat convert of h (4096x1024) then r (2048x1024).
// blocks [6144,7424): 64x64 transpose-convert tiles; t = blk-6144,
//   bx = t%80 selects {Wqkv: bx<48 | Wr: 48<=bx<64 | Wo: bx>=64}, y = t/80.
// Branch is blockIdx-uniform -> scalar branch (no lane-divergent MFMA hazard).
__global__ __launch_bounds__(256) void k_prep(const float* __restrict__ h,
                                              u16* __restrict__ hb,
                                              const float* __restrict__ r,
                                              u16* __restrict__ rb,
                                              const float* __restrict__ Wqkv,
                                              u16* __restrict__ Wqkv_t,
                                              const float* __restrict__ Wr,
                                              u16* __restrict__ Wr_t,
                                              const float* __restrict__ Wo,
                                              u16* __restrict__ Wo_t) {
  __shared__ u16 T[64][72];
  const int tid = threadIdx.x;
  const int blk = blockIdx.x;
  if (blk < 6144) {
    const int n4a = 4096 * 1024 / 4, n4b = 2048 * 1024 / 4;
    int i = blk * 256 + tid;
    if (i < n4a) {
      float4 v = ((const float4*)h)[i];
      ((ushort4*)hb)[i] = make_ushort4(f2bf(v.x), f2bf(v.y), f2bf(v.z), f2bf(v.w));
    } else {
      int j = i - n4a;
      if (j < n4b) {
        float4 v = ((const float4*)r)[j];
        ((ushort4*)rb)[j] = make_ushort4(f2bf(v.x), f2bf(v.y), f2bf(v.z), f2bf(v.w));
      }
    }
    return;
  }
  const int t = blk - 6144;
  const int bx = t % 80, y = t / 80;
  const float* src; u16* dst; int C, cx;
  if (bx < 48)      { src = Wqkv; dst = Wqkv_t; C = 3072; cx = bx; }
  else if (bx < 64) { src = Wr;   dst = Wr_t;   C = 1024; cx = bx - 48; }
  else              { src = Wo;   dst = Wo_t;   C = 1024; cx = bx - 64; }
  const int R = 1024;
  int r0 = y * 64, c0 = cx * 64;
#pragma unroll
  for (int p = 0; p < 4; ++p) {
    int f = p * 256 + tid;            // float4 id within 64x64 tile
    int rr = f >> 4, cc = (f & 15) * 4;
    float4 v = *(const float4*)(src + (size_t)(r0 + rr) * C + c0 + cc);
    T[rr][cc + 0] = f2bf(v.x); T[rr][cc + 1] = f2bf(v.y);
    T[rr][cc + 2] = f2bf(v.z); T[rr][cc + 3] = f2bf(v.w);
  }
  __syncthreads();
#pragma unroll
  for (int p = 0; p < 2; ++p) {
    int f = p * 256 + tid;            // u16x8 chunk id
    int c = f >> 3, rr = (f & 7) * 8;
    u16x8 v;
#pragma unroll
    for (int e = 0; e < 8; ++e) v[e] = T[rr + e][c];
    *(u16x8*)(dst + (size_t)(c0 + c) * R + r0 + rr) = v;
  }
}

// ---------------- GEMM body: C[M,N] = A[M,K] @ Bt[N,K]^T ----------------
// global_load_lds width=16 staging with BOTH-SIDES XOR swizzle (R16, proven):
// lane l loads global chunk (l&7)^(l>>3) -> LDS slot (r,c) holds chunk c^r;
// fragment read at row R fetches chunk kc^(R&7) -> 2-way reads.
template <int RES>
__device__ __forceinline__ void gemm_body(const u16* __restrict__ A,
                                          const u16* __restrict__ Bt,
                                          u16* __restrict__ Cb,
                                          float* __restrict__ Cf,
                                          const float* __restrict__ res,
                                          int M, int N, int K,
                                          int bx, int by,
                                          u16* As, u16* Bs) {
  const int tid = threadIdx.x;
  const int l = tid & 63, wv = tid >> 6;
  const int g = l >> 4, c16 = l & 15;
  const int m0 = bx * 128, n0 = by * 128;
  const int wr = (wv >> 1) * 64, wc = (wv & 1) * 64;
  const int lrow = l >> 3;                 // 0..7 within 8-row slot
  const int lchunk = (l & 7) ^ lrow;       // pre-swizzled source chunk
  f32x4 acc[4][4] = {};
  for (int k0 = 0; k0 < K; k0 += 64) {
    __syncthreads();
    // 16 slots of 8 rows x 64 cols (1KB); wave wv owns slots 4wv..4wv+3
#pragma unroll
    for (int p = 0; p < 4; ++p) {
      int slot = wv * 4 + p;
      int row = slot * 8 + lrow;
      gload_lds16(A + (size_t)(m0 + row) * K + k0 + lchunk * 8, &As[slot * 512]);
      gload_lds16(Bt + (size_t)(n0 + row) * K + k0 + lchunk * 8, &Bs[slot * 512]);
    }
    __syncthreads();  // compiler drains vmcnt(0) before barrier
#pragma unroll
    for (int ks = 0; ks < 2; ++ks) {
      s16x8 af[4], bf[4];
      const int rc = c16 & 7;
#pragma unroll
      for (int fr = 0; fr < 4; ++fr)
        af[fr] = *(const s16x8*)&As[(wr + fr * 16 + c16) * 64 +
                                    (((ks * 4 + g) ^ rc) * 8)];
#pragma unroll
      for (int fc = 0; fc < 4; ++fc)
        bf[fc] = *(const s16x8*)&Bs[(wc + fc * 16 + c16) * 64 +
                                    (((ks * 4 + g) ^ rc) * 8)];
#pragma unroll
      for (int fr = 0; fr < 4; ++fr)
#pragma unroll
        for (int fc = 0; fc < 4; ++fc)
          acc[fr][fc] = __builtin_amdgcn_mfma_f32_16x16x32_bf16(af[fr], bf[fc],
                                                                acc[fr][fc], 0, 0, 0);
    }
  }
#pragma unroll
  for (int fr = 0; fr < 4; ++fr)
#pragma unroll
    for (int fc = 0; fc < 4; ++fc)
#pragma unroll
      for (int reg = 0; reg < 4; ++reg) {
        int row = m0 + wr + fr * 16 + g * 4 + reg;
        int col = n0 + wc + fc * 16 + c16;
        float v = acc[fr][fc][reg];
        if (RES) Cf[(size_t)row * N + col] = v + res[(size_t)row * N + col];
        else     Cb[(size_t)row * N + col] = f2bf(v);
      }
}

// merged qkv + rk GEMMs (independent; both RES=0).
// blocks [0,768): qkv (M=4096,N=3072): bx=blk&31, by=blk>>5.
// blocks [768,896): rk (M=2048,N=1024): bx=t&15, by=t>>4.
__global__ __launch_bounds__(256) void k_gemm2(const u16* __restrict__ hb,
                                               const u16* __restrict__ Wqkv_t,
                                               u16* __restrict__ qkv,
                                               const u16* __restrict__ rb,
                                               const u16* __restrict__ Wr_t,
                                               u16* __restrict__ rk) {
  __shared__ u16 As[128 * 64];
  __shared__ u16 Bs[128 * 64];
  const int blk = blockIdx.x;
  if (blk < 768) {
    gemm_body<0>(hb, Wqkv_t, qkv, nullptr, nullptr, 4096, 3072, 1024,
                 blk & 31, blk >> 5, As, Bs);
  } else {
    const int t = blk - 768;
    gemm_body<0>(rb, Wr_t, rk, nullptr, nullptr, 2048, 1024, 1024,
                 t & 15, t >> 4, As, Bs);
  }
}

// Wo GEMM with residual (RES=1), separate (depends on attn output)
__global__ __launch_bounds__(256) void k_gemm_res(const u16* __restrict__ av,
                                                  const u16* __restrict__ Wo_t,
                                                  float* __restrict__ tmp,
                                                  const float* __restrict__ h) {
  __shared__ u16 As[128 * 64];
  __shared__ u16 Bs[128 * 64];
  gemm_body<1>(av, Wo_t, nullptr, tmp, h, 4096, 1024, 1024,
               blockIdx.x, blockIdx.y, As, Bs);
}

// ---------------- build V^T [b][n][d][j] from qkv ----------------
__global__ __launch_bounds__(256) void k_vt(const u16* __restrict__ qkv,
                                            u16* __restrict__ vT) {
  __shared__ u16 T[64][72];
  const int tid = threadIdx.x;
  const int j0 = blockIdx.x * 64;
  const int n = blockIdx.y & 15, b = blockIdx.y >> 4;
#pragma unroll
  for (int p = 0; p < 2; ++p) {
    int f = p * 256 + tid;
    int r = f >> 3, cc = (f & 7) * 8;
    *(u16x8*)&T[r][cc] =
        *(const u16x8*)(qkv + ((size_t)((j0 + r) * 2 + b)) * 3072 + 2048 + n * 64 + cc);
  }
  __syncthreads();
#pragma unroll
  for (int p = 0; p < 2; ++p) {
    int f = p * 256 + tid;
    int d = f >> 3, jc = (f & 7) * 8;
    u16x8 v;
#pragma unroll
    for (int e = 0; e < 8; ++e) v[e] = T[jc + e][d];
    *(u16x8*)(vT + ((size_t)((b * 16 + n) * 64 + d)) * 2048 + j0 + jc) = v;
  }
}

// ---------------- fused rel-attention (flash-style, KVBLK=128, swapped MFMA) ---
// R15/R16/R18 exact (172.5 us, best verified): swapped-operand structure,
// write-address rel-shift bake, static-shift softmax (bounded scores),
// K/V/rk register prefetch under PV, setprio on MFMA clusters.
__global__ __launch_bounds__(256) void k_attn(const u16* __restrict__ qkv,
                                              const u16* __restrict__ rk,
                                              const u16* __restrict__ vT,
                                              const float* __restrict__ rwb,
                                              const float* __restrict__ rrb,
                                              u16* __restrict__ av) {
  __shared__ u16 Kt[128][72];    // K tile [j][d]
  __shared__ u16 Vt[64][136];    // V^T tile [d][j]
  __shared__ u16 St2[65 * 200];  // shifted band, physical row p = QR[p-1+delta]
  __shared__ u16 Pt[4][16][136]; // P strips, per wave [row=c16][jj]

  const int tid = threadIdx.x;
  const int l = tid & 63, wv = tid >> 6;
  const int g = l >> 4, c16 = l & 15;
  // XCD-aware swizzle: 4 consecutive bn per XCD -> K/V/rk L2-resident
  const int s = blockIdx.x;
  const int y = (s & 7) + 8 * (s >> 8);  // bn
  const int x = (s >> 3) & 31;           // i-tile
  const int i0 = x * 64;
  const int n = y & 15, b = y >> 4;
  const int ii = wv * 16 + c16;          // this lane's q-row (softmax domain)
  const f32x4 zero4 = {0.f, 0.f, 0.f, 0.f};
  const s16x8 zero8 = {0, 0, 0, 0, 0, 0, 0, 0};

  // ---- loop-invariant register fragments ----
  s16x8 qw[2];
  {
    int i = i0 + wv * 16 + c16;
    const u16* src = qkv + ((size_t)(i * 2 + b)) * 3072 + n * 64;
#pragma unroll
    for (int ks = 0; ks < 2; ++ks) {
      int d0 = ks * 32 + g * 8;
      u16x8 raw = *(const u16x8*)(src + d0);
      u16x8 wq;
#pragma unroll
      for (int e = 0; e < 8; ++e)
        wq[e] = f2bf(bf2f(raw[e]) + rwb[n * 64 + d0 + e]);
      qw[ks] = __builtin_bit_cast(s16x8, wq);
    }
  }
  s16x8 qr_b[4][2];
#pragma unroll
  for (int rb2 = 0; rb2 < 4; ++rb2) {
    int i = i0 + rb2 * 16 + c16;
    const u16* src = qkv + ((size_t)(i * 2 + b)) * 3072 + n * 64;
#pragma unroll
    for (int ks = 0; ks < 2; ++ks) {
      int d0 = ks * 32 + g * 8;
      u16x8 raw = *(const u16x8*)(src + d0);
      u16x8 wq;
#pragma unroll
      for (int e = 0; e < 8; ++e)
        wq[e] = f2bf(bf2f(raw[e]) + rrb[n * 64 + d0 + e]);
      qr_b[rb2][ks] = __builtin_bit_cast(s16x8, wq);
    }
  }
  s16x8 q64[2];
  {
    int i = i0 + 64; if (i > SEQ - 1) i = SEQ - 1;
    const u16* src = qkv + ((size_t)(i * 2 + b)) * 3072 + n * 64;
#pragma unroll
    for (int ks = 0; ks < 2; ++ks) {
      int d0 = ks * 32 + g * 8;
      u16x8 raw = *(const u16x8*)(src + d0);
      u16x8 wq;
#pragma unroll
      for (int e = 0; e < 8; ++e)
        wq[e] = f2bf(bf2f(raw[e]) + rrb[n * 64 + d0 + e]);
      q64[ks] = __builtin_bit_cast(s16x8, wq);
    }
  }

  // prefetch registers (issued during previous iteration's PV)
  u16x8 kpre[4], vpre[4];
  s16x8 rpre[3][2];
  auto issue_loads = [&](int j0n) {
#pragma unroll
    for (int p = 0; p < 4; ++p) {
      int f = p * 256 + tid;
      kpre[p] = *(const u16x8*)(qkv + ((size_t)((j0n + (f >> 3)) * 2 + b)) * 3072 +
                                1024 + n * 64 + (f & 7) * 8);
    }
#pragma unroll
    for (int p = 0; p < 4; ++p) {
      int f = p * 256 + tid;
      vpre[p] = *(const u16x8*)(vT + ((size_t)((b * 16 + n) * 64 + (f >> 4))) * 2048 +
                                j0n + (f & 15) * 8);
    }
#pragma unroll
    for (int c3 = 0; c3 < 3; ++c3) {
      int w = (wv * 3 + c3) * 16 + c16;
      int u = j0n - i0 - 63 + w;
      int c = (u <= 0) ? (u + (SEQ - 1)) : (u - 2);
      const u16* p = rk + (size_t)(c < 0 ? 0 : c) * 1024 + n * 64;
      rpre[c3][0] = *(const s16x8*)(p + g * 8);
      rpre[c3][1] = *(const s16x8*)(p + 32 + g * 8);
      if (c < 0) { rpre[c3][0] = zero8; rpre[c3][1] = zero8; }
    }
  };

  float l_sum = 0.f;
  f32x4 o_acc[4];
#pragma unroll
  for (int r2 = 0; r2 < 4; ++r2) o_acc[r2] = zero4;

  issue_loads(0);

  for (int it = 0; it < 16; ++it) {
    const int j0 = it * 128;
    const int wbthr = (64 + i0 - j0) >> 4;  // delta(wb) = (wb >= wbthr)
    __syncthreads();  // prev-iter St2/Kt/Vt reads complete

    // ds-write staged K/V (vmcnt hidden under previous PV)
#pragma unroll
    for (int p = 0; p < 4; ++p) {
      int f = p * 256 + tid;
      *(u16x8*)&Kt[f >> 3][(f & 7) * 8] = kpre[p];
    }
#pragma unroll
    for (int p = 0; p < 4; ++p) {
      int f = p * 256 + tid;
      *(u16x8*)&Vt[f >> 4][(f & 15) * 8] = vpre[p];
    }

    // QR_sw: D[w in regs][r in lanes]; rel-shift baked into WRITE ADDRESS:
    // physical row = r + 1 - delta(wb)  (wave-uniform offset, no dual frags)
#pragma unroll
    for (int c3 = 0; c3 < 3; ++c3) {
      const int wb = wv * 3 + c3;
      const int du = (wb >= wbthr) ? 1 : 0;  // wave-uniform
#pragma unroll
      for (int rb2 = 0; rb2 < 4; ++rb2) {
        f32x4 q = zero4;
        q = __builtin_amdgcn_mfma_f32_16x16x32_bf16(rpre[c3][0], qr_b[rb2][0], q, 0, 0, 0);
        q = __builtin_amdgcn_mfma_f32_16x16x32_bf16(rpre[c3][1], qr_b[rb2][1], q, 0, 0, 0);
        uint2 pk;
        pk.x = pack2(q[0], q[1]);
        pk.y = pack2(q[2], q[3]);
        // row 0 (rb2=0,c16=0,du=1) is the discard slot; rows 1..64 are live
        *(uint2*)&St2[(rb2 * 16 + c16 + 1 - du) * 200 + wb * 16 + g * 4] = pk;
      }
      // q64 extra row (QR[64][w]) -> physical row 64, only used where delta=1
      {
        f32x4 q = zero4;
        q = __builtin_amdgcn_mfma_f32_16x16x32_bf16(rpre[c3][0], q64[0], q, 0, 0, 0);
        q = __builtin_amdgcn_mfma_f32_16x16x32_bf16(rpre[c3][1], q64[1], q, 0, 0, 0);
        if (du && c16 == 0) {
          uint2 pk;
          pk.x = pack2(q[0], q[1]);
          pk.y = pack2(q[2], q[3]);
          *(uint2*)&St2[64 * 200 + wb * 16 + g * 4] = pk;
        }
      }
    }
    __syncthreads();  // Kt, Vt, St2 visible

    // AC_sw = mfma(K, Q): lane c16 = ii, regs = jj = fj*16 + g*4 + reg
    f32x4 sc[8];
#pragma unroll
    for (int fj = 0; fj < 8; ++fj) sc[fj] = zero4;
    __builtin_amdgcn_s_setprio(1);
#pragma unroll
    for (int ks = 0; ks < 2; ++ks)
#pragma unroll
      for (int fj = 0; fj < 8; ++fj) {
        s16x8 kf = *(const s16x8*)&Kt[fj * 16 + c16][ks * 32 + g * 8];
        sc[fj] = __builtin_amdgcn_mfma_f32_16x16x32_bf16(kf, qw[ks], sc[fj], 0, 0, 0);
      }
    __builtin_amdgcn_s_setprio(0);

    // gather BD: physical row ii+1, col w = jj-ii+63
    // offset = (ii+1)*200 + jj - ii + 63 = ii*199 + 263 + fj*16 + g*4 + reg
    {
      const u16* Sb = &St2[ii * 199 + 263 + g * 4];
#pragma unroll
      for (int fj = 0; fj < 8; ++fj)
#pragma unroll
        for (int reg = 0; reg < 4; ++reg)
          sc[fj][reg] += bf2f(Sb[fj * 16 + reg]);
    }

    // static-shift softmax: p = exp2(s * KEXP) directly (bounded scores)
    float rs = 0.f;
#pragma unroll
    for (int fj = 0; fj < 8; ++fj)
#pragma unroll
      for (int reg = 0; reg < 4; ++reg) {
        float p = __builtin_amdgcn_exp2f(sc[fj][reg] * KEXP);
        rs += p;
        sc[fj][reg] = p;  // reuse sc as P
      }
    rs += __shfl_xor(rs, 16);
    rs += __shfl_xor(rs, 32);
    l_sum += rs;

    // P -> own strip (aligned b64), then read back as A-frags (same wave)
#pragma unroll
    for (int fj = 0; fj < 8; ++fj) {
      uint2 pk;
      pk.x = pack2(sc[fj][0], sc[fj][1]);
      pk.y = pack2(sc[fj][2], sc[fj][3]);
      *(uint2*)&Pt[wv][c16][fj * 16 + g * 4] = pk;
    }

    // prefetch next tile's K/V/rk while PV runs
    if (it < 15) issue_loads(j0 + 128);

    // PV: O += P @ V (A = P strip, row = c16 = ii)
    __builtin_amdgcn_s_setprio(1);
#pragma unroll
    for (int ks = 0; ks < 4; ++ks) {
      s16x8 pa = *(const s16x8*)&Pt[wv][c16][ks * 32 + g * 8];
#pragma unroll
      for (int fd = 0; fd < 4; ++fd) {
        s16x8 vb = *(const s16x8*)&Vt[fd * 16 + c16][ks * 32 + g * 8];
        o_acc[fd] = __builtin_amdgcn_mfma_f32_16x16x32_bf16(pa, vb, o_acc[fd], 0, 0, 0);
      }
    }
    __builtin_amdgcn_s_setprio(0);
  }

  // epilogue: transpose 1/l across lanes (rows in reg-dim)
  float linv = 1.0f / l_sum;
  float linv_t[4];
#pragma unroll
  for (int reg = 0; reg < 4; ++reg)
    linv_t[reg] = __shfl(linv, g * 4 + reg, 64);
#pragma unroll
  for (int reg = 0; reg < 4; ++reg) {
    int i = i0 + wv * 16 + g * 4 + reg;
    u16* dst = av + ((size_t)(i * 2 + b)) * 1024 + n * 64;
#pragma unroll
    for (int fd = 0; fd < 4; ++fd)
      dst[fd * 16 + c16] = f2bf(o_acc[fd][reg] * linv_t[reg]);
  }
}

// ---------------- LayerNorm over rows of tmp (= attn_out + h) ----------------
__global__ __launch_bounds__(256) void k_ln(const float* __restrict__ tmp,
                                            const float* __restrict__ gamma,
                                            const float* __restrict__ beta,
                                            float* __restrict__ out) {
  __shared__ float r1[4], r2[4];
  const int row = blockIdx.x, tid = threadIdx.x;
  const float* x = tmp + (size_t)row * 1024;
  float4 v = *(const float4*)(x + tid * 4);
  float s1 = v.x + v.y + v.z + v.w;
  float s2 = v.x * v.x + v.y * v.y + v.z * v.z + v.w * v.w;
#pragma unroll
  for (int off = 1; off < 64; off <<= 1) {
    s1 += __shfl_xor(s1, off, 64);
    s2 += __shfl_xor(s2, off, 64);
  }
  if ((tid & 63) == 0) { r1[tid >> 6] = s1; r2[tid >> 6] = s2; }
  __syncthreads();
  s1 = r1[0] + r1[1] + r1[2] + r1[3];
  s2 = r2[0] + r2[1] + r2[2] + r2[3];
  float mu = s1 * (1.f / 1024.f);
  float var = s2 * (1.f / 1024.f) - mu * mu;
  float rstd = rsqrtf(var + 1e-6f);
  float4 gm = *(const float4*)(gamma + tid * 4);
  float4 bt = *(const float4*)(beta + tid * 4);
  float4 o;
  o.x = (v.x - mu) * rstd * gm.x + bt.x;
  o.y = (v.y - mu) * rstd * gm.y + bt.y;
  o.z = (v.z - mu) * rstd * gm.z + bt.z;
  o.w = (v.w - mu) * rstd * gm.w + bt.w;
  *(float4*)(out + (size_t)row * 1024 + tid * 4) = o;
}

// ---------------- launch ----------------
extern "C" void kernel_launch(void* const* d_in, const int* in_sizes, int n_in,
                              void* d_out, int out_size, void* d_ws, size_t ws_size,
                              hipStream_t stream) {
  const float* h    = (const float*)d_in[0];
  const float* r    = (const float*)d_in[1];
  const float* rwb  = (const float*)d_in[2];
  const float* rrb  = (const float*)d_in[3];
  const float* Wqkv = (const float*)d_in[4];
  const float* Wr   = (const float*)d_in[5];
  const float* Wo   = (const float*)d_in[6];
  const float* gam  = (const float*)d_in[7];
  const float* bet  = (const float*)d_in[8];
  float* out = (float*)d_out;

  u16* hb     = (u16*)d_ws;                          // 4096*1024
  u16* Wqkv_t = hb + (size_t)4096 * 1024;            // 3072*1024
  u16* Wr_t   = Wqkv_t + (size_t)3072 * 1024;        // 1024*1024
  u16* Wo_t   = Wr_t + (size_t)1024 * 1024;          // 1024*1024
  u16* rb     = Wo_t + (size_t)1024 * 1024;          // 2048*1024
  u16* qkv    = rb + (size_t)2048 * 1024;            // 4096*3072
  u16* rk     = qkv + (size_t)4096 * 3072;           // 2048*1024
  u16* vT     = rk + (size_t)2048 * 1024;            // 2*16*64*2048
  u16* av     = vT + (size_t)2 * 16 * 64 * 2048;     // 4096*1024
  float* tmp  = (float*)(av + (size_t)4096 * 1024);  // 4096*1024 f32

  k_prep<<<7424, 256, 0, stream>>>(h, hb, r, rb, Wqkv, Wqkv_t, Wr, Wr_t, Wo, Wo_t);
  k_gemm2<<<896, 256, 0, stream>>>(hb, Wqkv_t, qkv, rb, Wr_t, rk);
  k_vt<<<dim3(32, 32), 256, 0, stream>>>(qkv, vT);
  k_attn<<<1024, 256, 0, stream>>>(qkv, rk, vT, rwb, rrb, av);
  k_gemm_res<<<dim3(32, 8), 256, 0, stream>>>(av, Wo_t, tmp, h);
  k_ln<<<4096, 256, 0, stream>>>(tmp, gam, bet, out);
}

// Round 21
// 240.554 us; speedup vs baseline: 1.1422x; 1.0188x over previous
//
#include <hip/hip_runtime.h>
#include <hip/hip_bf16.h>

typedef unsigned short u16;
typedef __attribute__((ext_vector_type(8))) short s16x8;
typedef __attribute__((ext_vector_type(8))) unsigned short u16x8;
typedef __attribute__((ext_vector_type(4))) float f32x4;

#define SEQ 2048
#define KEXP 0.18033688011112042f  /* 0.125 * log2(e) */

__device__ __forceinline__ float bf2f(u16 x) {
  union { unsigned u; float f; } c; c.u = ((unsigned)x) << 16; return c.f;
}
// hardware bf16 convert (v_cvt_pk_bf16_f32 on gfx950)
__device__ __forceinline__ u16 f2bf(float f) {
  __hip_bfloat16 h = __float2bfloat16(f);
  return __builtin_bit_cast(u16, h);
}
__device__ __forceinline__ unsigned pack2(float a, float b) {
  return (unsigned)f2bf(a) | ((unsigned)f2bf(b) << 16);
}
// async global->LDS, 16B per lane; LDS dest = wave-uniform base + lane*16
__device__ __forceinline__ void gload_lds16(const u16* g, u16* l) {
  __builtin_amdgcn_global_load_lds(
      (const __attribute__((address_space(1))) void*)g,
      (__attribute__((address_space(3))) void*)l, 16, 0, 0);
}

// ---------------- merged prologue: flat converts + weight transposes ----------
__global__ __launch_bounds__(256) void k_prep(const float* __restrict__ h,
                                              u16* __restrict__ hb,
                                              const float* __restrict__ r,
                                              u16* __restrict__ rb,
                                              const float* __restrict__ Wqkv,
                                              u16* __restrict__ Wqkv_t,
                                              const float* __restrict__ Wr,
                                              u16* __restrict__ Wr_t,
                                              const float* __restrict__ Wo,
                                              u16* __restrict__ Wo_t) {
  __shared__ u16 T[64][72];
  const int tid = threadIdx.x;
  const int blk = blockIdx.x;
  if (blk < 6144) {
    const int n4a = 4096 * 1024 / 4, n4b = 2048 * 1024 / 4;
    int i = blk * 256 + tid;
    if (i < n4a) {
      float4 v = ((const float4*)h)[i];
      ((ushort4*)hb)[i] = make_ushort4(f2bf(v.x), f2bf(v.y), f2bf(v.z), f2bf(v.w));
    } else {
      int j = i - n4a;
      if (j < n4b) {
        float4 v = ((const float4*)r)[j];
        ((ushort4*)rb)[j] = make_ushort4(f2bf(v.x), f2bf(v.y), f2bf(v.z), f2bf(v.w));
      }
    }
    return;
  }
  const int t = blk - 6144;
  const int bx = t % 80, y = t / 80;
  const float* src; u16* dst; int C, cx;
  if (bx < 48)      { src = Wqkv; dst = Wqkv_t; C = 3072; cx = bx; }
  else if (bx < 64) { src = Wr;   dst = Wr_t;   C = 1024; cx = bx - 48; }
  else              { src = Wo;   dst = Wo_t;   C = 1024; cx = bx - 64; }
  const int R = 1024;
  int r0 = y * 64, c0 = cx * 64;
#pragma unroll
  for (int p = 0; p < 4; ++p) {
    int f = p * 256 + tid;
    int rr = f >> 4, cc = (f & 15) * 4;
    float4 v = *(const float4*)(src + (size_t)(r0 + rr) * C + c0 + cc);
    T[rr][cc + 0] = f2bf(v.x); T[rr][cc + 1] = f2bf(v.y);
    T[rr][cc + 2] = f2bf(v.z); T[rr][cc + 3] = f2bf(v.w);
  }
  __syncthreads();
#pragma unroll
  for (int p = 0; p < 2; ++p) {
    int f = p * 256 + tid;
    int c = f >> 3, rr = (f & 7) * 8;
    u16x8 v;
#pragma unroll
    for (int e = 0; e < 8; ++e) v[e] = T[rr + e][c];
    *(u16x8*)(dst + (size_t)(c0 + c) * R + r0 + rr) = v;
  }
}

// ---------------- GEMM body: C[M,N] = A[M,K] @ Bt[N,K]^T ----------------
// R16-proven gload_lds + both-sides XOR swizzle staging.
// MODE 0: bf16 C write. MODE 1: f32 + residual. MODE 2: TRANSPOSED bf16 write
// to vT (V-region of qkv GEMM; C itself never stored — k_vt eliminated).
template <int MODE>
__device__ __forceinline__ void gemm_body(const u16* __restrict__ A,
                                          const u16* __restrict__ Bt,
                                          u16* __restrict__ Cb,
                                          float* __restrict__ Cf,
                                          const float* __restrict__ res,
                                          u16* __restrict__ vt,
                                          int M, int N, int K,
                                          int bx, int by, u16* SMEM) {
  u16* As = SMEM;            // 8192 u16
  u16* Bs = SMEM + 8192;     // 8192 u16
  const int tid = threadIdx.x;
  const int l = tid & 63, wv = tid >> 6;
  const int g = l >> 4, c16 = l & 15;
  const int m0 = bx * 128, n0 = by * 128;
  const int wr = (wv >> 1) * 64, wc = (wv & 1) * 64;
  const int lrow = l >> 3;
  const int lchunk = (l & 7) ^ lrow;
  f32x4 acc[4][4] = {};
  for (int k0 = 0; k0 < K; k0 += 64) {
    __syncthreads();
#pragma unroll
    for (int p = 0; p < 4; ++p) {
      int slot = wv * 4 + p;
      int row = slot * 8 + lrow;
      gload_lds16(A + (size_t)(m0 + row) * K + k0 + lchunk * 8, &As[slot * 512]);
      gload_lds16(Bt + (size_t)(n0 + row) * K + k0 + lchunk * 8, &Bs[slot * 512]);
    }
    __syncthreads();
#pragma unroll
    for (int ks = 0; ks < 2; ++ks) {
      s16x8 af[4], bf[4];
      const int rc = c16 & 7;
#pragma unroll
      for (int fr = 0; fr < 4; ++fr)
        af[fr] = *(const s16x8*)&As[(wr + fr * 16 + c16) * 64 +
                                    (((ks * 4 + g) ^ rc) * 8)];
#pragma unroll
      for (int fc = 0; fc < 4; ++fc)
        bf[fc] = *(const s16x8*)&Bs[(wc + fc * 16 + c16) * 64 +
                                    (((ks * 4 + g) ^ rc) * 8)];
#pragma unroll
      for (int fr = 0; fr < 4; ++fr)
#pragma unroll
        for (int fc = 0; fc < 4; ++fc)
          acc[fr][fc] = __builtin_amdgcn_mfma_f32_16x16x32_bf16(af[fr], bf[fc],
                                                                acc[fr][fc], 0, 0, 0);
    }
  }
  if (MODE < 2) {
#pragma unroll
    for (int fr = 0; fr < 4; ++fr)
#pragma unroll
      for (int fc = 0; fc < 4; ++fc)
#pragma unroll
        for (int reg = 0; reg < 4; ++reg) {
          int row = m0 + wr + fr * 16 + g * 4 + reg;
          int col = n0 + wc + fc * 16 + c16;
          float v = acc[fr][fc][reg];
          if (MODE == 1) Cf[(size_t)row * N + col] = v + res[(size_t)row * N + col];
          else           Cb[(size_t)row * N + col] = f2bf(v);
        }
  } else {
    // transposed epilogue: C tile (128 tokens-rows x 128 V-cols) -> vT.
    // Stage bf16 tile into SMEM [128][128] with col-rotate swizzle
    // col' = (col + row) & 127 (bijective per row; spreads the fixed-column
    // transpose reads across banks).
    __syncthreads();  // all waves' As/Bs fragment reads complete
    u16* Tt = SMEM;   // 16384 u16 = full 32KB
#pragma unroll
    for (int fr = 0; fr < 4; ++fr)
#pragma unroll
      for (int fc = 0; fc < 4; ++fc)
#pragma unroll
        for (int reg = 0; reg < 4; ++reg) {
          int lr = wr + fr * 16 + g * 4 + reg;       // local row 0..127
          int lc = wc + fc * 16 + c16;               // local col 0..127
          Tt[lr * 128 + ((lc + lr) & 127)] = f2bf(acc[fr][fc][reg]);
        }
    __syncthreads();
    // read transposed + write vT[((b*16+n)*64+d)][bx*64 + j], j in [0,64)
    const int nbase = (n0 - 2048) >> 6;  // global n of nh=0
#pragma unroll
    for (int p = 0; p < 8; ++p) {
      int rowc = p * 32 + (tid >> 3);    // 0..255 = (b,nh,d)
      int bb = rowc >> 7, nh = (rowc >> 6) & 1, d = rowc & 63;
      int chunk = tid & 7;
      u16x8 v;
#pragma unroll
      for (int rr = 0; rr < 8; ++rr) {
        int j = chunk * 8 + rr;
        int lr = j * 2 + bb;
        int lc = nh * 64 + d;
        v[rr] = Tt[lr * 128 + ((lc + lr) & 127)];
      }
      size_t vrow = (size_t)((bb * 16 + nbase + nh) * 64 + d);
      *(u16x8*)(vt + vrow * 2048 + bx * 64 + chunk * 8) = v;
    }
  }
}

// merged qkv + rk GEMMs. blocks [0,768): qkv (M=4096,N=3072), bx=blk&31,
// by=blk>>5; by>=16 are V columns -> MODE 2 (write vT directly, skip qkv).
// blocks [768,896): rk (M=2048,N=1024), MODE 0.
__global__ __launch_bounds__(256) void k_gemm2(const u16* __restrict__ hb,
                                               const u16* __restrict__ Wqkv_t,
                                               u16* __restrict__ qkv,
                                               const u16* __restrict__ rb,
                                               const u16* __restrict__ Wr_t,
                                               u16* __restrict__ rk,
                                               u16* __restrict__ vT) {
  __shared__ u16 SMEM[16384];
  const int blk = blockIdx.x;
  if (blk < 512) {
    gemm_body<0>(hb, Wqkv_t, qkv, nullptr, nullptr, nullptr, 4096, 3072, 1024,
                 blk & 31, blk >> 5, SMEM);
  } else if (blk < 768) {
    gemm_body<2>(hb, Wqkv_t, nullptr, nullptr, nullptr, vT, 4096, 3072, 1024,
                 blk & 31, blk >> 5, SMEM);
  } else {
    const int t = blk - 768;
    gemm_body<0>(rb, Wr_t, rk, nullptr, nullptr, nullptr, 2048, 1024, 1024,
                 t & 15, t >> 4, SMEM);
  }
}

// Wo GEMM with residual (MODE 1), separate (depends on attn output)
__global__ __launch_bounds__(256) void k_gemm_res(const u16* __restrict__ av,
                                                  const u16* __restrict__ Wo_t,
                                                  float* __restrict__ tmp,
                                                  const float* __restrict__ h) {
  __shared__ u16 SMEM[16384];
  gemm_body<1>(av, Wo_t, nullptr, tmp, h, nullptr, 4096, 1024, 1024,
               blockIdx.x, blockIdx.y, SMEM);
}

// ---------------- fused rel-attention (flash-style, KVBLK=128, swapped MFMA) ---
// R15/R16/R18 exact (172.5 us, best verified).
__global__ __launch_bounds__(256) void k_attn(const u16* __restrict__ qkv,
                                              const u16* __restrict__ rk,
                                              const u16* __restrict__ vT,
                                              const float* __restrict__ rwb,
                                              const float* __restrict__ rrb,
                                              u16* __restrict__ av) {
  __shared__ u16 Kt[128][72];    // K tile [j][d]
  __shared__ u16 Vt[64][136];    // V^T tile [d][j]
  __shared__ u16 St2[65 * 200];  // shifted band, physical row p = QR[p-1+delta]
  __shared__ u16 Pt[4][16][136]; // P strips, per wave [row=c16][jj]

  const int tid = threadIdx.x;
  const int l = tid & 63, wv = tid >> 6;
  const int g = l >> 4, c16 = l & 15;
  // XCD-aware swizzle: 4 consecutive bn per XCD -> K/V/rk L2-resident
  const int s = blockIdx.x;
  const int y = (s & 7) + 8 * (s >> 8);  // bn
  const int x = (s >> 3) & 31;           // i-tile
  const int i0 = x * 64;
  const int n = y & 15, b = y >> 4;
  const int ii = wv * 16 + c16;          // this lane's q-row (softmax domain)
  const f32x4 zero4 = {0.f, 0.f, 0.f, 0.f};
  const s16x8 zero8 = {0, 0, 0, 0, 0, 0, 0, 0};

  // ---- loop-invariant register fragments ----
  s16x8 qw[2];
  {
    int i = i0 + wv * 16 + c16;
    const u16* src = qkv + ((size_t)(i * 2 + b)) * 3072 + n * 64;
#pragma unroll
    for (int ks = 0; ks < 2; ++ks) {
      int d0 = ks * 32 + g * 8;
      u16x8 raw = *(const u16x8*)(src + d0);
      u16x8 wq;
#pragma unroll
      for (int e = 0; e < 8; ++e)
        wq[e] = f2bf(bf2f(raw[e]) + rwb[n * 64 + d0 + e]);
      qw[ks] = __builtin_bit_cast(s16x8, wq);
    }
  }
  s16x8 qr_b[4][2];
#pragma unroll
  for (int rb2 = 0; rb2 < 4; ++rb2) {
    int i = i0 + rb2 * 16 + c16;
    const u16* src = qkv + ((size_t)(i * 2 + b)) * 3072 + n * 64;
#pragma unroll
    for (int ks = 0; ks < 2; ++ks) {
      int d0 = ks * 32 + g * 8;
      u16x8 raw = *(const u16x8*)(src + d0);
      u16x8 wq;
#pragma unroll
      for (int e = 0; e < 8; ++e)
        wq[e] = f2bf(bf2f(raw[e]) + rrb[n * 64 + d0 + e]);
      qr_b[rb2][ks] = __builtin_bit_cast(s16x8, wq);
    }
  }
  s16x8 q64[2];
  {
    int i = i0 + 64; if (i > SEQ - 1) i = SEQ - 1;
    const u16* src = qkv + ((size_t)(i * 2 + b)) * 3072 + n * 64;
#pragma unroll
    for (int ks = 0; ks < 2; ++ks) {
      int d0 = ks * 32 + g * 8;
      u16x8 raw = *(const u16x8*)(src + d0);
      u16x8 wq;
#pragma unroll
      for (int e = 0; e < 8; ++e)
        wq[e] = f2bf(bf2f(raw[e]) + rrb[n * 64 + d0 + e]);
      q64[ks] = __builtin_bit_cast(s16x8, wq);
    }
  }

  // prefetch registers (issued during previous iteration's PV)
  u16x8 kpre[4], vpre[4];
  s16x8 rpre[3][2];
  auto issue_loads = [&](int j0n) {
#pragma unroll
    for (int p = 0; p < 4; ++p) {
      int f = p * 256 + tid;
      kpre[p] = *(const u16x8*)(qkv + ((size_t)((j0n + (f >> 3)) * 2 + b)) * 3072 +
                                1024 + n * 64 + (f & 7) * 8);
    }
#pragma unroll
    for (int p = 0; p < 4; ++p) {
      int f = p * 256 + tid;
      vpre[p] = *(const u16x8*)(vT + ((size_t)((b * 16 + n) * 64 + (f >> 4))) * 2048 +
                                j0n + (f & 15) * 8);
    }
#pragma unroll
    for (int c3 = 0; c3 < 3; ++c3) {
      int w = (wv * 3 + c3) * 16 + c16;
      int u = j0n - i0 - 63 + w;
      int c = (u <= 0) ? (u + (SEQ - 1)) : (u - 2);
      const u16* p = rk + (size_t)(c < 0 ? 0 : c) * 1024 + n * 64;
      rpre[c3][0] = *(const s16x8*)(p + g * 8);
      rpre[c3][1] = *(const s16x8*)(p + 32 + g * 8);
      if (c < 0) { rpre[c3][0] = zero8; rpre[c3][1] = zero8; }
    }
  };

  float l_sum = 0.f;
  f32x4 o_acc[4];
#pragma unroll
  for (int r2 = 0; r2 < 4; ++r2) o_acc[r2] = zero4;

  issue_loads(0);

  for (int it = 0; it < 16; ++it) {
    const int j0 = it * 128;
    const int wbthr = (64 + i0 - j0) >> 4;  // delta(wb) = (wb >= wbthr)
    __syncthreads();  // prev-iter St2/Kt/Vt reads complete

    // ds-write staged K/V (vmcnt hidden under previous PV)
#pragma unroll
    for (int p = 0; p < 4; ++p) {
      int f = p * 256 + tid;
      *(u16x8*)&Kt[f >> 3][(f & 7) * 8] = kpre[p];
    }
#pragma unroll
    for (int p = 0; p < 4; ++p) {
      int f = p * 256 + tid;
      *(u16x8*)&Vt[f >> 4][(f & 15) * 8] = vpre[p];
    }

    // QR_sw: D[w in regs][r in lanes]; rel-shift baked into WRITE ADDRESS:
    // physical row = r + 1 - delta(wb)  (wave-uniform offset, no dual frags)
#pragma unroll
    for (int c3 = 0; c3 < 3; ++c3) {
      const int wb = wv * 3 + c3;
      const int du = (wb >= wbthr) ? 1 : 0;  // wave-uniform
#pragma unroll
      for (int rb2 = 0; rb2 < 4; ++rb2) {
        f32x4 q = zero4;
        q = __builtin_amdgcn_mfma_f32_16x16x32_bf16(rpre[c3][0], qr_b[rb2][0], q, 0, 0, 0);
        q = __builtin_amdgcn_mfma_f32_16x16x32_bf16(rpre[c3][1], qr_b[rb2][1], q, 0, 0, 0);
        uint2 pk;
        pk.x = pack2(q[0], q[1]);
        pk.y = pack2(q[2], q[3]);
        // row 0 (rb2=0,c16=0,du=1) is the discard slot; rows 1..64 are live
        *(uint2*)&St2[(rb2 * 16 + c16 + 1 - du) * 200 + wb * 16 + g * 4] = pk;
      }
      // q64 extra row (QR[64][w]) -> physical row 64, only used where delta=1
      {
        f32x4 q = zero4;
        q = __builtin_amdgcn_mfma_f32_16x16x32_bf16(rpre[c3][0], q64[0], q, 0, 0, 0);
        q = __builtin_amdgcn_mfma_f32_16x16x32_bf16(rpre[c3][1], q64[1], q, 0, 0, 0);
        if (du && c16 == 0) {
          uint2 pk;
          pk.x = pack2(q[0], q[1]);
          pk.y = pack2(q[2], q[3]);
          *(uint2*)&St2[64 * 200 + wb * 16 + g * 4] = pk;
        }
      }
    }
    __syncthreads();  // Kt, Vt, St2 visible

    // AC_sw = mfma(K, Q): lane c16 = ii, regs = jj = fj*16 + g*4 + reg
    f32x4 sc[8];
#pragma unroll
    for (int fj = 0; fj < 8; ++fj) sc[fj] = zero4;
    __builtin_amdgcn_s_setprio(1);
#pragma unroll
    for (int ks = 0; ks < 2; ++ks)
#pragma unroll
      for (int fj = 0; fj < 8; ++fj) {
        s16x8 kf = *(const s16x8*)&Kt[fj * 16 + c16][ks * 32 + g * 8];
        sc[fj] = __builtin_amdgcn_mfma_f32_16x16x32_bf16(kf, qw[ks], sc[fj], 0, 0, 0);
      }
    __builtin_amdgcn_s_setprio(0);

    // gather BD: physical row ii+1, col w = jj-ii+63
    // offset = (ii+1)*200 + jj - ii + 63 = ii*199 + 263 + fj*16 + g*4 + reg
    {
      const u16* Sb = &St2[ii * 199 + 263 + g * 4];
#pragma unroll
      for (int fj = 0; fj < 8; ++fj)
#pragma unroll
        for (int reg = 0; reg < 4; ++reg)
          sc[fj][reg] += bf2f(Sb[fj * 16 + reg]);
    }

    // static-shift softmax: p = exp2(s * KEXP) directly (bounded scores)
    float rs = 0.f;
#pragma unroll
    for (int fj = 0; fj < 8; ++fj)
#pragma unroll
      for (int reg = 0; reg < 4; ++reg) {
        float p = __builtin_amdgcn_exp2f(sc[fj][reg] * KEXP);
        rs += p;
        sc[fj][reg] = p;  // reuse sc as P
      }
    rs += __shfl_xor(rs, 16);
    rs += __shfl_xor(rs, 32);
    l_sum += rs;

    // P -> own strip (aligned b64), then read back as A-frags (same wave)
#pragma unroll
    for (int fj = 0; fj < 8; ++fj) {
      uint2 pk;
      pk.x = pack2(sc[fj][0], sc[fj][1]);
      pk.y = pack2(sc[fj][2], sc[fj][3]);
      *(uint2*)&Pt[wv][c16][fj * 16 + g * 4] = pk;
    }

    // prefetch next tile's K/V/rk while PV runs
    if (it < 15) issue_loads(j0 + 128);

    // PV: O += P @ V (A = P strip, row = c16 = ii)
    __builtin_amdgcn_s_setprio(1);
#pragma unroll
    for (int ks = 0; ks < 4; ++ks) {
      s16x8 pa = *(const s16x8*)&Pt[wv][c16][ks * 32 + g * 8];
#pragma unroll
      for (int fd = 0; fd < 4; ++fd) {
        s16x8 vb = *(const s16x8*)&Vt[fd * 16 + c16][ks * 32 + g * 8];
        o_acc[fd] = __builtin_amdgcn_mfma_f32_16x16x32_bf16(pa, vb, o_acc[fd], 0, 0, 0);
      }
    }
    __builtin_amdgcn_s_setprio(0);
  }

  // epilogue: transpose 1/l across lanes (rows in reg-dim)
  float linv = 1.0f / l_sum;
  float linv_t[4];
#pragma unroll
  for (int reg = 0; reg < 4; ++reg)
    linv_t[reg] = __shfl(linv, g * 4 + reg, 64);
#pragma unroll
  for (int reg = 0; reg < 4; ++reg) {
    int i = i0 + wv * 16 + g * 4 + reg;
    u16* dst = av + ((size_t)(i * 2 + b)) * 1024 + n * 64;
#pragma unroll
    for (int fd = 0; fd < 4; ++fd)
      dst[fd * 16 + c16] = f2bf(o_acc[fd][reg] * linv_t[reg]);
  }
}

// ---------------- LayerNorm over rows of tmp (= attn_out + h) ----------------
__global__ __launch_bounds__(256) void k_ln(const float* __restrict__ tmp,
                                            const float* __restrict__ gamma,
                                            const float* __restrict__ beta,
                                            float* __restrict__ out) {
  __shared__ float r1[4], r2[4];
  const int row = blockIdx.x, tid = threadIdx.x;
  const float* x = tmp + (size_t)row * 1024;
  float4 v = *(const float4*)(x + tid * 4);
  float s1 = v.x + v.y + v.z + v.w;
  float s2 = v.x * v.x + v.y * v.y + v.z * v.z + v.w * v.w;
#pragma unroll
  for (int off = 1; off < 64; off <<= 1) {
    s1 += __shfl_xor(s1, off, 64);
    s2 += __shfl_xor(s2, off, 64);
  }
  if ((tid & 63) == 0) { r1[tid >> 6] = s1; r2[tid >> 6] = s2; }
  __syncthreads();
  s1 = r1[0] + r1[1] + r1[2] + r1[3];
  s2 = r2[0] + r2[1] + r2[2] + r2[3];
  float mu = s1 * (1.f / 1024.f);
  float var = s2 * (1.f / 1024.f) - mu * mu;
  float rstd = rsqrtf(var + 1e-6f);
  float4 gm = *(const float4*)(gamma + tid * 4);
  float4 bt = *(const float4*)(beta + tid * 4);
  float4 o;
  o.x = (v.x - mu) * rstd * gm.x + bt.x;
  o.y = (v.y - mu) * rstd * gm.y + bt.y;
  o.z = (v.z - mu) * rstd * gm.z + bt.z;
  o.w = (v.w - mu) * rstd * gm.w + bt.w;
  *(float4*)(out + (size_t)row * 1024 + tid * 4) = o;
}

// ---------------- launch ----------------
extern "C" void kernel_launch(void* const* d_in, const int* in_sizes, int n_in,
                              void* d_out, int out_size, void* d_ws, size_t ws_size,
                              hipStream_t stream) {
  const float* h    = (const float*)d_in[0];
  const float* r    = (const float*)d_in[1];
  const float* rwb  = (const float*)d_in[2];
  const float* rrb  = (const float*)d_in[3];
  const float* Wqkv = (const float*)d_in[4];
  const float* Wr   = (const float*)d_in[5];
  const float* Wo   = (const float*)d_in[6];
  const float* gam  = (const float*)d_in[7];
  const float* bet  = (const float*)d_in[8];
  float* out = (float*)d_out;

  u16* hb     = (u16*)d_ws;                          // 4096*1024
  u16* Wqkv_t = hb + (size_t)4096 * 1024;            // 3072*1024
  u16* Wr_t   = Wqkv_t + (size_t)3072 * 1024;        // 1024*1024
  u16* Wo_t   = Wr_t + (size_t)1024 * 1024;          // 1024*1024
  u16* rb     = Wo_t + (size_t)1024 * 1024;          // 2048*1024
  u16* qkv    = rb + (size_t)2048 * 1024;            // 4096*3072
  u16* rk     = qkv + (size_t)4096 * 3072;           // 2048*1024
  u16* vT     = rk + (size_t)2048 * 1024;            // 2*16*64*2048
  u16* av     = vT + (size_t)2 * 16 * 64 * 2048;     // 4096*1024
  float* tmp  = (float*)(av + (size_t)4096 * 1024);  // 4096*1024 f32

  k_prep<<<7424, 256, 0, stream>>>(h, hb, r, rb, Wqkv, Wqkv_t, Wr, Wr_t, Wo, Wo_t);
  k_gemm2<<<896, 256, 0, stream>>>(hb, Wqkv_t, qkv, rb, Wr_t, rk, vT);
  k_attn<<<1024, 256, 0, stream>>>(qkv, rk, vT, rwb, rrb, av);
  k_gemm_res<<<dim3(32, 8), 256, 0, stream>>>(av, Wo_t, tmp, h);
  k_ln<<<4096, 256, 0, stream>>>(tmp, gam, bet, out);
}